// Round 3
// baseline (446.313 us; speedup 1.0000x reference)
//
#include <hip/hip_runtime.h>

#define SEQ 2048
#define DMODEL 1024
#define NH 16
#define DH 64

typedef __attribute__((ext_vector_type(8))) short bf16x8;
typedef __attribute__((ext_vector_type(4))) float floatx4;
typedef unsigned short u16;
typedef unsigned int u32;

__device__ __forceinline__ u16 f2bf(float f) {
    union { u32 u; float f; } v; v.f = f;
    u32 r = v.u + 0x7fffu + ((v.u >> 16) & 1u);   // round-to-nearest-even
    return (u16)(r >> 16);
}

union Pack8 { u16 h[8]; uint4 q; };

// load 8 contiguous f32, convert to 8 bf16 packed in a uint4
__device__ __forceinline__ uint4 cvt8(const float* __restrict__ p) {
    float4 a = *(const float4*)p;
    float4 b = *(const float4*)(p + 4);
    Pack8 pk;
    pk.h[0] = f2bf(a.x); pk.h[1] = f2bf(a.y); pk.h[2] = f2bf(a.z); pk.h[3] = f2bf(a.w);
    pk.h[4] = f2bf(b.x); pk.h[5] = f2bf(b.y); pk.h[6] = f2bf(b.z); pk.h[7] = f2bf(b.w);
    return pk.q;
}

// C = A @ W^T + bias.  A: [4096,1024] (f32, or bf16 if A_BF16). W: [1024,1024] f32.
// MODE 0: bf16 out [B,H,S,Dh]; MODE 1: bf16 out [B,H,Dh,S]; MODE 2: f32 out [B,S,D].
template<int MODE, bool A_BF16>
__global__ __launch_bounds__(256) void gemm_bt(
    const void* __restrict__ Av, const float* __restrict__ W,
    const float* __restrict__ bias, void* __restrict__ outv)
{
    __shared__ __align__(16) u16 As[128 * 32];
    __shared__ __align__(16) u16 Bs[128 * 32];
    const int tid  = threadIdx.x;
    const int l    = tid & 63;
    const int w    = tid >> 6;
    const int lm   = l & 15;
    const int quad = l >> 4;
    const int wr   = (w >> 1) * 64;   // wave row offset in 128-tile
    const int wc   = (w & 1) * 64;    // wave col offset
    const int bm   = blockIdx.y * 128;
    const int bn   = blockIdx.x * 128;

    floatx4 acc[4][4];
#pragma unroll
    for (int i = 0; i < 4; i++)
#pragma unroll
        for (int j = 0; j < 4; j++) acc[i][j] = (floatx4){0.f, 0.f, 0.f, 0.f};

    for (int kt = 0; kt < DMODEL; kt += 32) {
        __syncthreads();
#pragma unroll
        for (int j = 0; j < 2; j++) {
            int ch = j * 256 + tid;         // 0..511 : 8-element chunks
            int row = ch >> 2, c8 = ch & 3; // row 0..127, chunk 0..3
            // W staging: f32 -> bf16
            *(uint4*)(Bs + row * 32 + c8 * 8) =
                cvt8(W + (size_t)(bn + row) * DMODEL + kt + c8 * 8);
            // A staging
            if (A_BF16) {
                *(uint4*)(As + row * 32 + c8 * 8) =
                    *(const uint4*)((const u16*)Av + (size_t)(bm + row) * DMODEL + kt + c8 * 8);
            } else {
                *(uint4*)(As + row * 32 + c8 * 8) =
                    cvt8((const float*)Av + (size_t)(bm + row) * DMODEL + kt + c8 * 8);
            }
        }
        __syncthreads();

        bf16x8 af[4], bfr[4];
#pragma unroll
        for (int mi = 0; mi < 4; mi++)
            af[mi] = *(const bf16x8*)(As + (wr + mi * 16 + lm) * 32 + quad * 8);
#pragma unroll
        for (int ni = 0; ni < 4; ni++)
            bfr[ni] = *(const bf16x8*)(Bs + (wc + ni * 16 + lm) * 32 + quad * 8);
#pragma unroll
        for (int mi = 0; mi < 4; mi++)
#pragma unroll
            for (int ni = 0; ni < 4; ni++)
                acc[mi][ni] = __builtin_amdgcn_mfma_f32_16x16x32_bf16(
                    af[mi], bfr[ni], acc[mi][ni], 0, 0, 0);
    }

    // epilogue: bias add, layout-specific store
#pragma unroll
    for (int ni = 0; ni < 4; ni++) {
        int col = bn + wc + ni * 16 + lm;
        float bv = bias[col];
#pragma unroll
        for (int mi = 0; mi < 4; mi++) {
#pragma unroll
            for (int r = 0; r < 4; r++) {
                int rowg = bm + wr + mi * 16 + quad * 4 + r;
                float v = acc[mi][ni][r] + bv;
                if (MODE == 0) {
                    int b = rowg >> 11, s = rowg & 2047, h = col >> 6, d = col & 63;
                    ((u16*)outv)[((size_t)(b * NH + h) * SEQ + s) * DH + d] = f2bf(v);
                } else if (MODE == 1) {
                    int b = rowg >> 11, s = rowg & 2047, h = col >> 6, d = col & 63;
                    ((u16*)outv)[((size_t)(b * NH + h) * DH + d) * SEQ + s] = f2bf(v);
                } else {
                    ((float*)outv)[(size_t)rowg * DMODEL + col] = v;
                }
            }
        }
    }
}

// Flash attention: grid (S/64, B*NH), block 256 (4 waves; wave w owns q-rows w*16..w*16+15).
// q,k: [B,H,S,Dh] bf16;  vt: [B,H,Dh,S] bf16;  out: [B,S,D] bf16.
__global__ __launch_bounds__(256) void attn_kernel(
    const u16* __restrict__ q, const u16* __restrict__ k,
    const u16* __restrict__ vt, u16* __restrict__ out)
{
    __shared__ __align__(16) u16 Qs[64 * 64];
    __shared__ __align__(16) u16 Ks[64 * 64];
    __shared__ __align__(16) u16 Vs[64 * 64];     // V^T tile: [d][key]
    __shared__ __align__(16) u16 Ps[4][16 * 64];  // per-wave P scratch [m][key]
    const int tid  = threadIdx.x;
    const int l    = tid & 63;
    const int w    = tid >> 6;
    const int lm   = l & 15;
    const int quad = l >> 4;
    const int qt   = blockIdx.x;   // q-tile
    const int bh   = blockIdx.y;   // b*NH + h
    const int b    = bh >> 4, h = bh & 15;

    const u16* qg = q + ((size_t)bh * SEQ + qt * 64) * DH;
#pragma unroll
    for (int j = 0; j < 2; j++) {
        int e = (j * 256 + tid) * 8;
        *(uint4*)(Qs + e) = *(const uint4*)(qg + e);
    }
    __syncthreads();
    bf16x8 aq0 = *(const bf16x8*)(Qs + (w * 16 + lm) * 64 + quad * 8);
    bf16x8 aq1 = *(const bf16x8*)(Qs + (w * 16 + lm) * 64 + 32 + quad * 8);

    floatx4 O[4];
#pragma unroll
    for (int di = 0; di < 4; di++) O[di] = (floatx4){0.f, 0.f, 0.f, 0.f};
    float mrun[4], lrun[4];
#pragma unroll
    for (int r = 0; r < 4; r++) { mrun[r] = -1e30f; lrun[r] = 0.f; }

    for (int kt2 = 0; kt2 < SEQ / 64; kt2++) {
        __syncthreads();
        const u16* kg = k + ((size_t)bh * SEQ + kt2 * 64) * DH;
#pragma unroll
        for (int j = 0; j < 2; j++) {
            int e = (j * 256 + tid) * 8;
            *(uint4*)(Ks + e) = *(const uint4*)(kg + e);
        }
#pragma unroll
        for (int j = 0; j < 2; j++) {
            int ch = j * 256 + tid;
            int row = ch >> 3, c8 = ch & 7;   // d-row 0..63, chunk 0..7
            *(uint4*)(Vs + row * 64 + c8 * 8) =
                *(const uint4*)(vt + ((size_t)bh * DH + row) * SEQ + kt2 * 64 + c8 * 8);
        }
        __syncthreads();

        // S = (q k^T) * 0.125
        floatx4 Sc[4];
#pragma unroll
        for (int ni = 0; ni < 4; ni++) {
            bf16x8 bk0 = *(const bf16x8*)(Ks + (ni * 16 + lm) * 64 + quad * 8);
            bf16x8 bk1 = *(const bf16x8*)(Ks + (ni * 16 + lm) * 64 + 32 + quad * 8);
            floatx4 c = (floatx4){0.f, 0.f, 0.f, 0.f};
            c = __builtin_amdgcn_mfma_f32_16x16x32_bf16(aq0, bk0, c, 0, 0, 0);
            c = __builtin_amdgcn_mfma_f32_16x16x32_bf16(aq1, bk1, c, 0, 0, 0);
            Sc[ni] = c;
        }
#pragma unroll
        for (int ni = 0; ni < 4; ni++)
#pragma unroll
            for (int r = 0; r < 4; r++) Sc[ni][r] *= 0.125f;

        // online softmax: row = quad*4+r, its 16 cols live in the 16 lanes of this quad group
        float alpha[4], P[4][4];
#pragma unroll
        for (int r = 0; r < 4; r++) {
            float m0 = fmaxf(fmaxf(Sc[0][r], Sc[1][r]), fmaxf(Sc[2][r], Sc[3][r]));
            m0 = fmaxf(m0, __shfl_xor(m0, 1));
            m0 = fmaxf(m0, __shfl_xor(m0, 2));
            m0 = fmaxf(m0, __shfl_xor(m0, 4));
            m0 = fmaxf(m0, __shfl_xor(m0, 8));
            float mn = fmaxf(mrun[r], m0);
            alpha[r] = __expf(mrun[r] - mn);
            mrun[r] = mn;
        }
#pragma unroll
        for (int ni = 0; ni < 4; ni++)
#pragma unroll
            for (int r = 0; r < 4; r++) P[ni][r] = __expf(Sc[ni][r] - mrun[r]);
#pragma unroll
        for (int r = 0; r < 4; r++) {
            float s0 = (P[0][r] + P[1][r]) + (P[2][r] + P[3][r]);
            s0 += __shfl_xor(s0, 1);
            s0 += __shfl_xor(s0, 2);
            s0 += __shfl_xor(s0, 4);
            s0 += __shfl_xor(s0, 8);
            lrun[r] = lrun[r] * alpha[r] + s0;
        }
#pragma unroll
        for (int di = 0; di < 4; di++)
#pragma unroll
            for (int r = 0; r < 4; r++) O[di][r] *= alpha[r];

        // P: C-layout -> A-layout via per-wave LDS scratch
        u16* ps = Ps[w];
#pragma unroll
        for (int ni = 0; ni < 4; ni++)
#pragma unroll
            for (int r = 0; r < 4; r++)
                ps[(quad * 4 + r) * 64 + ni * 16 + lm] = f2bf(P[ni][r]);
        __syncthreads();
        bf16x8 ap0 = *(const bf16x8*)(ps + lm * 64 + quad * 8);
        bf16x8 ap1 = *(const bf16x8*)(ps + lm * 64 + 32 + quad * 8);

        // O += P @ V  (B-operand from V^T tile)
#pragma unroll
        for (int di = 0; di < 4; di++) {
            bf16x8 bv0 = *(const bf16x8*)(Vs + (di * 16 + lm) * 64 + quad * 8);
            bf16x8 bv1 = *(const bf16x8*)(Vs + (di * 16 + lm) * 64 + 32 + quad * 8);
            O[di] = __builtin_amdgcn_mfma_f32_16x16x32_bf16(ap0, bv0, O[di], 0, 0, 0);
            O[di] = __builtin_amdgcn_mfma_f32_16x16x32_bf16(ap1, bv1, O[di], 0, 0, 0);
        }
    }

    // epilogue: O / l, store bf16 [B,S,D]
#pragma unroll
    for (int di = 0; di < 4; di++) {
#pragma unroll
        for (int r = 0; r < 4; r++) {
            int s = qt * 64 + w * 16 + quad * 4 + r;
            int d = di * 16 + lm;
            float v = O[di][r] / lrun[r];
            out[((size_t)b * SEQ + s) * DMODEL + h * DH + d] = f2bf(v);
        }
    }
}

extern "C" void kernel_launch(void* const* d_in, const int* in_sizes, int n_in,
                              void* d_out, int out_size, void* d_ws, size_t ws_size,
                              hipStream_t stream) {
    (void)in_sizes; (void)n_in; (void)out_size; (void)ws_size;
    const float* Q  = (const float*)d_in[0];
    const float* K  = (const float*)d_in[1];
    const float* V  = (const float*)d_in[2];
    const float* Wq = (const float*)d_in[3];
    const float* bq = (const float*)d_in[4];
    const float* Wk = (const float*)d_in[5];
    const float* bk = (const float*)d_in[6];
    const float* Wv = (const float*)d_in[7];
    const float* bv = (const float*)d_in[8];
    const float* Wo = (const float*)d_in[9];
    const float* bo = (const float*)d_in[10];

    const size_t NEL = (size_t)2 * NH * SEQ * DH;  // 4,194,304 elements
    u16* qws  = (u16*)d_ws;          //  8 MB bf16 q  [B,H,S,Dh]
    u16* kws  = qws + NEL;           //  8 MB bf16 k  [B,H,S,Dh]
    u16* vtws = kws + NEL;           //  8 MB bf16 v^T [B,H,Dh,S]
    u16* aws  = vtws + NEL;          //  8 MB bf16 attn out [B,S,D]

    dim3 gg(DMODEL / 128, (2 * SEQ) / 128), bb(256);
    gemm_bt<0, false><<<gg, bb, 0, stream>>>(Q, Wq, bq, qws);
    gemm_bt<0, false><<<gg, bb, 0, stream>>>(K, Wk, bk, kws);
    gemm_bt<1, false><<<gg, bb, 0, stream>>>(V, Wv, bv, vtws);
    attn_kernel<<<dim3(SEQ / 64, 2 * NH), bb, 0, stream>>>(qws, kws, vtws, aws);
    gemm_bt<2, true><<<gg, bb, 0, stream>>>(aws, Wo, bo, d_out);
}

// Round 4
// 312.841 us; speedup vs baseline: 1.4266x; 1.4266x over previous
//
#include <hip/hip_runtime.h>

#define SEQ 2048
#define DMODEL 1024
#define NH 16
#define DH 64

typedef __attribute__((ext_vector_type(8))) short bf16x8;
typedef __attribute__((ext_vector_type(4))) float floatx4;
typedef unsigned short u16;
typedef unsigned int u32;

typedef const void __attribute__((address_space(1)))* as1cvp;
typedef void __attribute__((address_space(3)))* as3vp;

// async global->LDS, 16B per lane; LDS dest = wave-uniform base + lane*16
__device__ __forceinline__ void glds16(const void* g, void* l) {
    __builtin_amdgcn_global_load_lds((as1cvp)g, (as3vp)l, 16, 0, 0);
}

__device__ __forceinline__ u16 f2bf(float f) {
    union { u32 u; float f; } v; v.f = f;
    u32 r = v.u + 0x7fffu + ((v.u >> 16) & 1u);   // RNE
    return (u16)(r >> 16);
}

union Pack8 { u16 h[8]; uint4 q; };

__device__ __forceinline__ uint4 cvt8(const float* __restrict__ p) {
    float4 a = *(const float4*)p;
    float4 b = *(const float4*)(p + 4);
    Pack8 pk;
    pk.h[0] = f2bf(a.x); pk.h[1] = f2bf(a.y); pk.h[2] = f2bf(a.z); pk.h[3] = f2bf(a.w);
    pk.h[4] = f2bf(b.x); pk.h[5] = f2bf(b.y); pk.h[6] = f2bf(b.z); pk.h[7] = f2bf(b.w);
    return pk.q;
}

// convert 4 weight matrices (each 1024x1024 f32) to bf16, packed [4][1024][1024]
__global__ __launch_bounds__(256) void cvt_w(
    const float* __restrict__ W0, const float* __restrict__ W1,
    const float* __restrict__ W2, const float* __restrict__ W3,
    u16* __restrict__ out)
{
    const float* src = (blockIdx.y == 0) ? W0 : (blockIdx.y == 1) ? W1
                     : (blockIdx.y == 2) ? W2 : W3;
    size_t i = ((size_t)blockIdx.x * 256 + threadIdx.x) * 8;
    *(uint4*)(out + (size_t)blockIdx.y * 1048576 + i) = cvt8(src + i);
}

// Batched QKV projection: z=0 -> q [B,H,S,Dh] (pre-scaled 1/8), z=1 -> k [B,H,S,Dh],
// z=2 -> v^T [B,H,Dh,S]. A f32, W bf16 (WBF) or f32.
template<bool WBF>
__global__ __launch_bounds__(256) void gemm_qkv(
    const float* __restrict__ Qf, const float* __restrict__ Kf, const float* __restrict__ Vf,
    const void* __restrict__ W0, const void* __restrict__ W1, const void* __restrict__ W2,
    const float* __restrict__ b0, const float* __restrict__ b1, const float* __restrict__ b2,
    u16* __restrict__ qo, u16* __restrict__ ko, u16* __restrict__ vto)
{
    __shared__ __align__(16) u16 As[128 * 32];
    __shared__ __align__(16) u16 Bs[128 * 32];
    const int tid = threadIdx.x, l = tid & 63, w = tid >> 6;
    const int lm = l & 15, quad = l >> 4;
    const int wr = (w >> 1) * 64, wc = (w & 1) * 64;
    const int bm = blockIdx.y * 128, bn = blockIdx.x * 128;
    const int z = blockIdx.z;
    const float* A    = (z == 0) ? Qf : (z == 1) ? Kf : Vf;
    const void* Wp    = (z == 0) ? W0 : (z == 1) ? W1 : W2;
    const float* bias = (z == 0) ? b0 : (z == 1) ? b1 : b2;

    floatx4 acc[4][4];
#pragma unroll
    for (int i = 0; i < 4; i++)
#pragma unroll
        for (int j = 0; j < 4; j++) acc[i][j] = (floatx4){0.f, 0.f, 0.f, 0.f};

    for (int kt = 0; kt < DMODEL; kt += 32) {
        __syncthreads();
#pragma unroll
        for (int j = 0; j < 2; j++) {
            int ch = j * 256 + tid, row = ch >> 2, c = ch & 3;
            *(uint4*)(As + ch * 8) = cvt8(A + (size_t)(bm + row) * DMODEL + kt + c * 8);
        }
        if (WBF) {
            const u16* Wb = (const u16*)Wp;
            glds16(Wb + (size_t)(bn + (tid >> 2)) * DMODEL + kt + (tid & 3) * 8, Bs + w * 512);
            glds16(Wb + (size_t)(bn + 64 + (tid >> 2)) * DMODEL + kt + (tid & 3) * 8, Bs + 2048 + w * 512);
        } else {
            const float* Wf = (const float*)Wp;
#pragma unroll
            for (int j = 0; j < 2; j++) {
                int ch = j * 256 + tid, row = ch >> 2, c = ch & 3;
                *(uint4*)(Bs + ch * 8) = cvt8(Wf + (size_t)(bn + row) * DMODEL + kt + c * 8);
            }
        }
        __syncthreads();

        bf16x8 af[4], bfr[4];
#pragma unroll
        for (int mi = 0; mi < 4; mi++)
            af[mi] = *(const bf16x8*)(As + (wr + mi * 16 + lm) * 32 + quad * 8);
#pragma unroll
        for (int ni = 0; ni < 4; ni++)
            bfr[ni] = *(const bf16x8*)(Bs + (wc + ni * 16 + lm) * 32 + quad * 8);
#pragma unroll
        for (int mi = 0; mi < 4; mi++)
#pragma unroll
            for (int ni = 0; ni < 4; ni++)
                acc[mi][ni] = __builtin_amdgcn_mfma_f32_16x16x32_bf16(
                    af[mi], bfr[ni], acc[mi][ni], 0, 0, 0);
    }

    const float sc = (z == 0) ? 0.125f : 1.0f;
    u16* outp = (z == 0) ? qo : (z == 1) ? ko : vto;
#pragma unroll
    for (int ni = 0; ni < 4; ni++) {
        int col = bn + wc + ni * 16 + lm;
        float bv = bias[col];
#pragma unroll
        for (int mi = 0; mi < 4; mi++) {
#pragma unroll
            for (int r = 0; r < 4; r++) {
                int rowg = bm + wr + mi * 16 + quad * 4 + r;
                float v = (acc[mi][ni][r] + bv) * sc;
                int b = rowg >> 11, s = rowg & 2047, h = col >> 6, d = col & 63;
                if (z < 2)
                    outp[((size_t)(b * NH + h) * SEQ + s) * DH + d] = f2bf(v);
                else
                    outp[((size_t)(b * NH + h) * DH + d) * SEQ + s] = f2bf(v);
            }
        }
    }
}

// O-projection: A bf16 [4096,1024], W bf16/f32 [1024,1024], out f32 [B,S,D]. 128x64 tiles.
template<bool WBF>
__global__ __launch_bounds__(256) void gemm_o(
    const u16* __restrict__ A, const void* __restrict__ Wp,
    const float* __restrict__ bias, float* __restrict__ out)
{
    __shared__ __align__(16) u16 As[128 * 32];
    __shared__ __align__(16) u16 Bs[64 * 32];
    const int tid = threadIdx.x, l = tid & 63, w = tid >> 6;
    const int lm = l & 15, quad = l >> 4;
    const int bm = blockIdx.y * 128, bn = blockIdx.x * 64;

    floatx4 acc[2][4];
#pragma unroll
    for (int i = 0; i < 2; i++)
#pragma unroll
        for (int j = 0; j < 4; j++) acc[i][j] = (floatx4){0.f, 0.f, 0.f, 0.f};

    for (int kt = 0; kt < DMODEL; kt += 32) {
        __syncthreads();
        glds16(A + (size_t)(bm + (tid >> 2)) * DMODEL + kt + (tid & 3) * 8, As + w * 512);
        glds16(A + (size_t)(bm + 64 + (tid >> 2)) * DMODEL + kt + (tid & 3) * 8, As + 2048 + w * 512);
        if (WBF) {
            glds16((const u16*)Wp + (size_t)(bn + (tid >> 2)) * DMODEL + kt + (tid & 3) * 8, Bs + w * 512);
        } else {
            *(uint4*)(Bs + tid * 8) =
                cvt8((const float*)Wp + (size_t)(bn + (tid >> 2)) * DMODEL + kt + (tid & 3) * 8);
        }
        __syncthreads();

        bf16x8 af[2], bfr[4];
#pragma unroll
        for (int mi = 0; mi < 2; mi++)
            af[mi] = *(const bf16x8*)(As + (w * 32 + mi * 16 + lm) * 32 + quad * 8);
#pragma unroll
        for (int ni = 0; ni < 4; ni++)
            bfr[ni] = *(const bf16x8*)(Bs + (ni * 16 + lm) * 32 + quad * 8);
#pragma unroll
        for (int mi = 0; mi < 2; mi++)
#pragma unroll
            for (int ni = 0; ni < 4; ni++)
                acc[mi][ni] = __builtin_amdgcn_mfma_f32_16x16x32_bf16(
                    af[mi], bfr[ni], acc[mi][ni], 0, 0, 0);
    }

#pragma unroll
    for (int ni = 0; ni < 4; ni++) {
        int col = bn + ni * 16 + lm;
        float bv = bias[col];
#pragma unroll
        for (int mi = 0; mi < 2; mi++) {
#pragma unroll
            for (int r = 0; r < 4; r++) {
                int rowg = bm + w * 32 + mi * 16 + quad * 4 + r;
                out[(size_t)rowg * DMODEL + col] = acc[mi][ni][r] + bv;
            }
        }
    }
}

// Flash attention v2: grid (SEQ/128, B*NH), 4 waves; wave w owns q-rows w*32..w*32+31.
// q pre-scaled by 1/8. Padded LDS rows (stride 72 u16). KV reg-prefetch.
#define SP 72
__global__ __launch_bounds__(256) void attn_kernel(
    const u16* __restrict__ q, const u16* __restrict__ k,
    const u16* __restrict__ vt, u16* __restrict__ out)
{
    __shared__ __align__(16) u16 Ks[64 * SP];
    __shared__ __align__(16) u16 Vs[64 * SP];
    __shared__ __align__(16) u16 Ps[4][32 * SP];  // per-wave P scratch; also Q staging
    const int tid = threadIdx.x, l = tid & 63, w = tid >> 6;
    const int lm = l & 15, quad = l >> 4;
    const int qt = blockIdx.x, bh = blockIdx.y;
    const int b = bh >> 4, h = bh & 15;

    // stage Q tile (128x64) into the Ps region, padded
    u16* Qstage = &Ps[0][0];
    const u16* qg = q + ((size_t)bh * SEQ + qt * 128) * DH;
#pragma unroll
    for (int j = 0; j < 4; j++) {
        int ch = j * 256 + tid, row = ch >> 3, c8 = ch & 7;
        *(uint4*)(Qstage + row * SP + c8 * 8) = *(const uint4*)(qg + row * DH + c8 * 8);
    }
    __syncthreads();
    // wave w's rows live exactly in Ps[w]; same-wave LDS ordering covers later P writes
    bf16x8 aq[2][2];
#pragma unroll
    for (int mi = 0; mi < 2; mi++)
#pragma unroll
        for (int kk = 0; kk < 2; kk++)
            aq[mi][kk] = *(const bf16x8*)(Qstage + (w * 32 + mi * 16 + lm) * SP + kk * 32 + quad * 8);

    floatx4 O[2][4];
#pragma unroll
    for (int mi = 0; mi < 2; mi++)
#pragma unroll
        for (int di = 0; di < 4; di++) O[mi][di] = (floatx4){0.f, 0.f, 0.f, 0.f};
    float mrun[2][4], lrun[2][4];
#pragma unroll
    for (int mi = 0; mi < 2; mi++)
#pragma unroll
        for (int r = 0; r < 4; r++) { mrun[mi][r] = -1e30f; lrun[mi][r] = 0.f; }

    const int prow = tid >> 3, pc = (tid & 7) * 8;
    const u16* kbase = k + (size_t)bh * SEQ * DH;
    const u16* vbase = vt + (size_t)bh * DH * SEQ;
    uint4 kr0, kr1, vr0, vr1;
    {   // prefetch t=0
        const u16* kg = kbase;
        kr0 = *(const uint4*)(kg + (size_t)prow * DH + pc);
        kr1 = *(const uint4*)(kg + (size_t)(prow + 32) * DH + pc);
        vr0 = *(const uint4*)(vbase + (size_t)prow * SEQ + pc);
        vr1 = *(const uint4*)(vbase + (size_t)(prow + 32) * SEQ + pc);
    }

    for (int t = 0; t < SEQ / 64; t++) {
        __syncthreads();   // previous tile's consumers done
        *(uint4*)(Ks + prow * SP + pc) = kr0;
        *(uint4*)(Ks + (prow + 32) * SP + pc) = kr1;
        *(uint4*)(Vs + prow * SP + pc) = vr0;
        *(uint4*)(Vs + (prow + 32) * SP + pc) = vr1;
        __syncthreads();
        if (t + 1 < SEQ / 64) {   // prefetch next tile; loads fly during compute
            const u16* kg = kbase + (size_t)(t + 1) * 64 * DH;
            kr0 = *(const uint4*)(kg + (size_t)prow * DH + pc);
            kr1 = *(const uint4*)(kg + (size_t)(prow + 32) * DH + pc);
            const u16* vg = vbase + (size_t)(t + 1) * 64;
            vr0 = *(const uint4*)(vg + (size_t)prow * SEQ + pc);
            vr1 = *(const uint4*)(vg + (size_t)(prow + 32) * SEQ + pc);
        }

        // S = q k^T  (scale folded into q)
        bf16x8 bk[4][2];
#pragma unroll
        for (int ni = 0; ni < 4; ni++)
#pragma unroll
            for (int kk = 0; kk < 2; kk++)
                bk[ni][kk] = *(const bf16x8*)(Ks + (ni * 16 + lm) * SP + kk * 32 + quad * 8);
        floatx4 Sc[2][4];
#pragma unroll
        for (int mi = 0; mi < 2; mi++)
#pragma unroll
            for (int ni = 0; ni < 4; ni++) {
                floatx4 c = (floatx4){0.f, 0.f, 0.f, 0.f};
                c = __builtin_amdgcn_mfma_f32_16x16x32_bf16(aq[mi][0], bk[ni][0], c, 0, 0, 0);
                c = __builtin_amdgcn_mfma_f32_16x16x32_bf16(aq[mi][1], bk[ni][1], c, 0, 0, 0);
                Sc[mi][ni] = c;
            }

        // online softmax (rows = quad*4+r within each mi block)
        float alpha[2][4];
#pragma unroll
        for (int mi = 0; mi < 2; mi++)
#pragma unroll
            for (int r = 0; r < 4; r++) {
                float m0 = fmaxf(fmaxf(Sc[mi][0][r], Sc[mi][1][r]),
                                 fmaxf(Sc[mi][2][r], Sc[mi][3][r]));
                m0 = fmaxf(m0, __shfl_xor(m0, 1));
                m0 = fmaxf(m0, __shfl_xor(m0, 2));
                m0 = fmaxf(m0, __shfl_xor(m0, 4));
                m0 = fmaxf(m0, __shfl_xor(m0, 8));
                float mn = fmaxf(mrun[mi][r], m0);
                alpha[mi][r] = __expf(mrun[mi][r] - mn);
                mrun[mi][r] = mn;
            }
#pragma unroll
        for (int mi = 0; mi < 2; mi++)
#pragma unroll
            for (int ni = 0; ni < 4; ni++)
#pragma unroll
                for (int r = 0; r < 4; r++)
                    Sc[mi][ni][r] = __expf(Sc[mi][ni][r] - mrun[mi][r]);
#pragma unroll
        for (int mi = 0; mi < 2; mi++)
#pragma unroll
            for (int r = 0; r < 4; r++) {
                float s0 = (Sc[mi][0][r] + Sc[mi][1][r]) + (Sc[mi][2][r] + Sc[mi][3][r]);
                s0 += __shfl_xor(s0, 1);
                s0 += __shfl_xor(s0, 2);
                s0 += __shfl_xor(s0, 4);
                s0 += __shfl_xor(s0, 8);
                lrun[mi][r] = lrun[mi][r] * alpha[mi][r] + s0;
            }
#pragma unroll
        for (int mi = 0; mi < 2; mi++)
#pragma unroll
            for (int di = 0; di < 4; di++)
#pragma unroll
                for (int r = 0; r < 4; r++) O[mi][di][r] *= alpha[mi][r];

        // P: C-layout -> A-layout via per-wave scratch (no block barrier needed)
        u16* ps = Ps[w];
#pragma unroll
        for (int mi = 0; mi < 2; mi++)
#pragma unroll
            for (int ni = 0; ni < 4; ni++)
#pragma unroll
                for (int r = 0; r < 4; r++)
                    ps[(mi * 16 + quad * 4 + r) * SP + ni * 16 + lm] = f2bf(Sc[mi][ni][r]);
        bf16x8 ap[2][2];
#pragma unroll
        for (int mi = 0; mi < 2; mi++)
#pragma unroll
            for (int kk = 0; kk < 2; kk++)
                ap[mi][kk] = *(const bf16x8*)(ps + (mi * 16 + lm) * SP + kk * 32 + quad * 8);

        // O += P @ V
        bf16x8 bv[4][2];
#pragma unroll
        for (int di = 0; di < 4; di++)
#pragma unroll
            for (int kk = 0; kk < 2; kk++)
                bv[di][kk] = *(const bf16x8*)(Vs + (di * 16 + lm) * SP + kk * 32 + quad * 8);
#pragma unroll
        for (int mi = 0; mi < 2; mi++)
#pragma unroll
            for (int di = 0; di < 4; di++) {
                O[mi][di] = __builtin_amdgcn_mfma_f32_16x16x32_bf16(ap[mi][0], bv[di][0], O[mi][di], 0, 0, 0);
                O[mi][di] = __builtin_amdgcn_mfma_f32_16x16x32_bf16(ap[mi][1], bv[di][1], O[mi][di], 0, 0, 0);
            }
    }

    // epilogue: O / l, store bf16 [B,S,D]
#pragma unroll
    for (int mi = 0; mi < 2; mi++)
#pragma unroll
        for (int di = 0; di < 4; di++)
#pragma unroll
            for (int r = 0; r < 4; r++) {
                int s = qt * 128 + w * 32 + mi * 16 + quad * 4 + r;
                int d = di * 16 + lm;
                float v = O[mi][di][r] / lrun[mi][r];
                out[((size_t)b * SEQ + s) * DMODEL + h * DH + d] = f2bf(v);
            }
}

extern "C" void kernel_launch(void* const* d_in, const int* in_sizes, int n_in,
                              void* d_out, int out_size, void* d_ws, size_t ws_size,
                              hipStream_t stream) {
    (void)in_sizes; (void)n_in; (void)out_size;
    const float* Q  = (const float*)d_in[0];
    const float* K  = (const float*)d_in[1];
    const float* V  = (const float*)d_in[2];
    const float* Wq = (const float*)d_in[3];
    const float* bq = (const float*)d_in[4];
    const float* Wk = (const float*)d_in[5];
    const float* bk = (const float*)d_in[6];
    const float* Wv = (const float*)d_in[7];
    const float* bv = (const float*)d_in[8];
    const float* Wo = (const float*)d_in[9];
    const float* bo = (const float*)d_in[10];

    const size_t NEL = (size_t)2 * NH * SEQ * DH;  // 4,194,304
    const bool big = ws_size >= (size_t)(5 * NEL) * 2;  // 41.9 MB: Wb + 4 buffers
    u16* base = (u16*)d_ws;
    u16 *Wb, *qws, *kws, *vtws, *aws;
    if (big) {
        Wb = base; qws = base + NEL; kws = qws + NEL; vtws = kws + NEL; aws = vtws + NEL;
    } else {
        Wb = nullptr; qws = base; kws = qws + NEL; vtws = kws + NEL; aws = vtws + NEL;
    }

    dim3 bb(256);
    if (big) {
        cvt_w<<<dim3(512, 4), bb, 0, stream>>>(Wq, Wk, Wv, Wo, Wb);
        gemm_qkv<true><<<dim3(8, 32, 3), bb, 0, stream>>>(
            Q, K, V, Wb, Wb + 1048576, Wb + 2097152, bq, bk, bv, qws, kws, vtws);
        attn_kernel<<<dim3(SEQ / 128, 2 * NH), bb, 0, stream>>>(qws, kws, vtws, aws);
        gemm_o<true><<<dim3(16, 32), bb, 0, stream>>>(aws, Wb + 3145728, bo, (float*)d_out);
    } else {
        gemm_qkv<false><<<dim3(8, 32, 3), bb, 0, stream>>>(
            Q, K, V, Wq, Wk, Wv, bq, bk, bv, qws, kws, vtws);
        attn_kernel<<<dim3(SEQ / 128, 2 * NH), bb, 0, stream>>>(qws, kws, vtws, aws);
        gemm_o<false><<<dim3(16, 32), bb, 0, stream>>>(aws, Wo, bo, (float*)d_out);
    }
}

// Round 5
// 307.296 us; speedup vs baseline: 1.4524x; 1.0180x over previous
//
#include <hip/hip_runtime.h>

#define SEQ 2048
#define DMODEL 1024
#define NH 16
#define DH 64

typedef __attribute__((ext_vector_type(8))) short bf16x8;
typedef __attribute__((ext_vector_type(4))) float floatx4;
typedef unsigned short u16;
typedef unsigned int u32;

typedef const void __attribute__((address_space(1)))* as1cvp;
typedef void __attribute__((address_space(3)))* as3vp;

// async global->LDS, 16B per lane; LDS dest = wave-uniform base + lane*16
__device__ __forceinline__ void glds16(const void* g, void* l) {
    __builtin_amdgcn_global_load_lds((as1cvp)g, (as3vp)l, 16, 0, 0);
}

__device__ __forceinline__ u16 f2bf(float f) {
    union { u32 u; float f; } v; v.f = f;
    u32 r = v.u + 0x7fffu + ((v.u >> 16) & 1u);   // RNE
    return (u16)(r >> 16);
}

union Pack8 { u16 h[8]; uint4 q; };

__device__ __forceinline__ uint4 cvt8(const float* __restrict__ p) {
    float4 a = *(const float4*)p;
    float4 b = *(const float4*)(p + 4);
    Pack8 pk;
    pk.h[0] = f2bf(a.x); pk.h[1] = f2bf(a.y); pk.h[2] = f2bf(a.z); pk.h[3] = f2bf(a.w);
    pk.h[4] = f2bf(b.x); pk.h[5] = f2bf(b.y); pk.h[6] = f2bf(b.z); pk.h[7] = f2bf(b.w);
    return pk.q;
}

// ---------------- full path: convert Q,K,V,Wq,Wk,Wv,Wo to bf16 once ----------------
// grid (2048, 7); y=0..2 -> Q/K/V (4M elems), y=3..6 -> W's (1M elems, only x<512 active)
__global__ __launch_bounds__(256) void cvt_all(
    const float* __restrict__ Q, const float* __restrict__ K, const float* __restrict__ V,
    const float* __restrict__ W0, const float* __restrict__ W1,
    const float* __restrict__ W2, const float* __restrict__ W3,
    u16* __restrict__ Qb, u16* __restrict__ Kb, u16* __restrict__ Vb,
    u16* __restrict__ Wb)
{
    const int y = blockIdx.y;
    const float* src; u16* dst;
    if (y == 0)      { src = Q;  dst = Qb; }
    else if (y == 1) { src = K;  dst = Kb; }
    else if (y == 2) { src = V;  dst = Vb; }
    else {
        if (blockIdx.x >= 512) return;
        src = (y == 3) ? W0 : (y == 4) ? W1 : (y == 5) ? W2 : W3;
        dst = Wb + (size_t)(y - 3) * 1048576;
    }
    size_t i = ((size_t)blockIdx.x * 256 + threadIdx.x) * 8;
    *(uint4*)(dst + i) = cvt8(src + i);
}

// legacy 42MB path: convert only weights
__global__ __launch_bounds__(256) void cvt_w(
    const float* __restrict__ W0, const float* __restrict__ W1,
    const float* __restrict__ W2, const float* __restrict__ W3,
    u16* __restrict__ out)
{
    const float* src = (blockIdx.y == 0) ? W0 : (blockIdx.y == 1) ? W1
                     : (blockIdx.y == 2) ? W2 : W3;
    size_t i = ((size_t)blockIdx.x * 256 + threadIdx.x) * 8;
    *(uint4*)(out + (size_t)blockIdx.y * 1048576 + i) = cvt8(src + i);
}

// q pre-scale: 1/sqrt(64) * log2(e), so attention can use exp2 directly
#define QSCALE 0.1803368801111244f

// ---------------- QKV projection, both operands bf16, pure glds16 staging ----------------
// z=0 -> q [B,H,S,Dh] (pre-scaled QSCALE), z=1 -> k [B,H,S,Dh], z=2 -> v^T [B,H,Dh,S]
__global__ __launch_bounds__(256) void gemm_qkv_bb(
    const u16* __restrict__ Qb, const u16* __restrict__ Kb, const u16* __restrict__ Vb,
    const u16* __restrict__ Wb,
    const float* __restrict__ b0, const float* __restrict__ b1, const float* __restrict__ b2,
    u16* __restrict__ qo, u16* __restrict__ ko, u16* __restrict__ vto)
{
    __shared__ __align__(16) u16 As[128 * 32];
    __shared__ __align__(16) u16 Bs[128 * 32];
    const int tid = threadIdx.x, l = tid & 63, w = tid >> 6;
    const int lm = l & 15, quad = l >> 4;
    const int wr = (w >> 1) * 64, wc = (w & 1) * 64;
    const int bm = blockIdx.y * 128, bn = blockIdx.x * 128;
    const int z = blockIdx.z;
    const u16* A      = (z == 0) ? Qb : (z == 1) ? Kb : Vb;
    const u16* W      = Wb + (size_t)z * 1048576;
    const float* bias = (z == 0) ? b0 : (z == 1) ? b1 : b2;

    const int srow = tid >> 2, scol = (tid & 3) * 8;

    floatx4 acc[4][4];
#pragma unroll
    for (int i = 0; i < 4; i++)
#pragma unroll
        for (int j = 0; j < 4; j++) acc[i][j] = (floatx4){0.f, 0.f, 0.f, 0.f};

    for (int kt = 0; kt < DMODEL; kt += 32) {
        __syncthreads();
        glds16(A + (size_t)(bm + srow) * DMODEL + kt + scol, As + w * 512);
        glds16(A + (size_t)(bm + 64 + srow) * DMODEL + kt + scol, As + 2048 + w * 512);
        glds16(W + (size_t)(bn + srow) * DMODEL + kt + scol, Bs + w * 512);
        glds16(W + (size_t)(bn + 64 + srow) * DMODEL + kt + scol, Bs + 2048 + w * 512);
        __syncthreads();

        bf16x8 af[4], bfr[4];
#pragma unroll
        for (int mi = 0; mi < 4; mi++)
            af[mi] = *(const bf16x8*)(As + (wr + mi * 16 + lm) * 32 + quad * 8);
#pragma unroll
        for (int ni = 0; ni < 4; ni++)
            bfr[ni] = *(const bf16x8*)(Bs + (wc + ni * 16 + lm) * 32 + quad * 8);
#pragma unroll
        for (int mi = 0; mi < 4; mi++)
#pragma unroll
            for (int ni = 0; ni < 4; ni++)
                acc[mi][ni] = __builtin_amdgcn_mfma_f32_16x16x32_bf16(
                    af[mi], bfr[ni], acc[mi][ni], 0, 0, 0);
    }

    const float sc = (z == 0) ? QSCALE : 1.0f;
    u16* outp = (z == 0) ? qo : (z == 1) ? ko : vto;
#pragma unroll
    for (int ni = 0; ni < 4; ni++) {
        int col = bn + wc + ni * 16 + lm;
        float bv = bias[col];
#pragma unroll
        for (int mi = 0; mi < 4; mi++) {
#pragma unroll
            for (int r = 0; r < 4; r++) {
                int rowg = bm + wr + mi * 16 + quad * 4 + r;
                float v = (acc[mi][ni][r] + bv) * sc;
                int b = rowg >> 11, s = rowg & 2047, h = col >> 6, d = col & 63;
                if (z < 2)
                    outp[((size_t)(b * NH + h) * SEQ + s) * DH + d] = f2bf(v);
                else
                    outp[((size_t)(b * NH + h) * DH + d) * SEQ + s] = f2bf(v);
            }
        }
    }
}

// ---------------- legacy QKV (A f32 converted in staging) ----------------
template<bool WBF>
__global__ __launch_bounds__(256) void gemm_qkv(
    const float* __restrict__ Qf, const float* __restrict__ Kf, const float* __restrict__ Vf,
    const void* __restrict__ W0, const void* __restrict__ W1, const void* __restrict__ W2,
    const float* __restrict__ b0, const float* __restrict__ b1, const float* __restrict__ b2,
    u16* __restrict__ qo, u16* __restrict__ ko, u16* __restrict__ vto)
{
    __shared__ __align__(16) u16 As[128 * 32];
    __shared__ __align__(16) u16 Bs[128 * 32];
    const int tid = threadIdx.x, l = tid & 63, w = tid >> 6;
    const int lm = l & 15, quad = l >> 4;
    const int wr = (w >> 1) * 64, wc = (w & 1) * 64;
    const int bm = blockIdx.y * 128, bn = blockIdx.x * 128;
    const int z = blockIdx.z;
    const float* A    = (z == 0) ? Qf : (z == 1) ? Kf : Vf;
    const void* Wp    = (z == 0) ? W0 : (z == 1) ? W1 : W2;
    const float* bias = (z == 0) ? b0 : (z == 1) ? b1 : b2;

    floatx4 acc[4][4];
#pragma unroll
    for (int i = 0; i < 4; i++)
#pragma unroll
        for (int j = 0; j < 4; j++) acc[i][j] = (floatx4){0.f, 0.f, 0.f, 0.f};

    for (int kt = 0; kt < DMODEL; kt += 32) {
        __syncthreads();
#pragma unroll
        for (int j = 0; j < 2; j++) {
            int ch = j * 256 + tid, row = ch >> 2, c = ch & 3;
            *(uint4*)(As + ch * 8) = cvt8(A + (size_t)(bm + row) * DMODEL + kt + c * 8);
        }
        if (WBF) {
            const u16* Wb = (const u16*)Wp;
            glds16(Wb + (size_t)(bn + (tid >> 2)) * DMODEL + kt + (tid & 3) * 8, Bs + w * 512);
            glds16(Wb + (size_t)(bn + 64 + (tid >> 2)) * DMODEL + kt + (tid & 3) * 8, Bs + 2048 + w * 512);
        } else {
            const float* Wf = (const float*)Wp;
#pragma unroll
            for (int j = 0; j < 2; j++) {
                int ch = j * 256 + tid, row = ch >> 2, c = ch & 3;
                *(uint4*)(Bs + ch * 8) = cvt8(Wf + (size_t)(bn + row) * DMODEL + kt + c * 8);
            }
        }
        __syncthreads();

        bf16x8 af[4], bfr[4];
#pragma unroll
        for (int mi = 0; mi < 4; mi++)
            af[mi] = *(const bf16x8*)(As + (wr + mi * 16 + lm) * 32 + quad * 8);
#pragma unroll
        for (int ni = 0; ni < 4; ni++)
            bfr[ni] = *(const bf16x8*)(Bs + (wc + ni * 16 + lm) * 32 + quad * 8);
#pragma unroll
        for (int mi = 0; mi < 4; mi++)
#pragma unroll
            for (int ni = 0; ni < 4; ni++)
                acc[mi][ni] = __builtin_amdgcn_mfma_f32_16x16x32_bf16(
                    af[mi], bfr[ni], acc[mi][ni], 0, 0, 0);
    }

    const float sc = (z == 0) ? QSCALE : 1.0f;
    u16* outp = (z == 0) ? qo : (z == 1) ? ko : vto;
#pragma unroll
    for (int ni = 0; ni < 4; ni++) {
        int col = bn + wc + ni * 16 + lm;
        float bv = bias[col];
#pragma unroll
        for (int mi = 0; mi < 4; mi++) {
#pragma unroll
            for (int r = 0; r < 4; r++) {
                int rowg = bm + wr + mi * 16 + quad * 4 + r;
                float v = (acc[mi][ni][r] + bv) * sc;
                int b = rowg >> 11, s = rowg & 2047, h = col >> 6, d = col & 63;
                if (z < 2)
                    outp[((size_t)(b * NH + h) * SEQ + s) * DH + d] = f2bf(v);
                else
                    outp[((size_t)(b * NH + h) * DH + d) * SEQ + s] = f2bf(v);
            }
        }
    }
}

// ---------------- O-projection: A bf16, W bf16/f32, out f32. 128x64 tiles ----------------
template<bool WBF>
__global__ __launch_bounds__(256) void gemm_o(
    const u16* __restrict__ A, const void* __restrict__ Wp,
    const float* __restrict__ bias, float* __restrict__ out)
{
    __shared__ __align__(16) u16 As[128 * 32];
    __shared__ __align__(16) u16 Bs[64 * 32];
    const int tid = threadIdx.x, l = tid & 63, w = tid >> 6;
    const int lm = l & 15, quad = l >> 4;
    const int bm = blockIdx.y * 128, bn = blockIdx.x * 64;

    floatx4 acc[2][4];
#pragma unroll
    for (int i = 0; i < 2; i++)
#pragma unroll
        for (int j = 0; j < 4; j++) acc[i][j] = (floatx4){0.f, 0.f, 0.f, 0.f};

    for (int kt = 0; kt < DMODEL; kt += 32) {
        __syncthreads();
        glds16(A + (size_t)(bm + (tid >> 2)) * DMODEL + kt + (tid & 3) * 8, As + w * 512);
        glds16(A + (size_t)(bm + 64 + (tid >> 2)) * DMODEL + kt + (tid & 3) * 8, As + 2048 + w * 512);
        if (WBF) {
            glds16((const u16*)Wp + (size_t)(bn + (tid >> 2)) * DMODEL + kt + (tid & 3) * 8, Bs + w * 512);
        } else {
            *(uint4*)(Bs + tid * 8) =
                cvt8((const float*)Wp + (size_t)(bn + (tid >> 2)) * DMODEL + kt + (tid & 3) * 8);
        }
        __syncthreads();

        bf16x8 af[2], bfr[4];
#pragma unroll
        for (int mi = 0; mi < 2; mi++)
            af[mi] = *(const bf16x8*)(As + (w * 32 + mi * 16 + lm) * 32 + quad * 8);
#pragma unroll
        for (int ni = 0; ni < 4; ni++)
            bfr[ni] = *(const bf16x8*)(Bs + (ni * 16 + lm) * 32 + quad * 8);
#pragma unroll
        for (int mi = 0; mi < 2; mi++)
#pragma unroll
            for (int ni = 0; ni < 4; ni++)
                acc[mi][ni] = __builtin_amdgcn_mfma_f32_16x16x32_bf16(
                    af[mi], bfr[ni], acc[mi][ni], 0, 0, 0);
    }

#pragma unroll
    for (int ni = 0; ni < 4; ni++) {
        int col = bn + ni * 16 + lm;
        float bv = bias[col];
#pragma unroll
        for (int mi = 0; mi < 2; mi++) {
#pragma unroll
            for (int r = 0; r < 4; r++) {
                int rowg = bm + w * 32 + mi * 16 + quad * 4 + r;
                out[(size_t)rowg * DMODEL + col] = acc[mi][ni][r] + bv;
            }
        }
    }
}

// ---------------- Flash attention: grid (SEQ/128, B*NH), 4 waves, 32 q-rows/wave ----------------
// q pre-scaled by QSCALE (1/8 * log2e) -> use exp2. Padded LDS rows (stride 72 u16).
#define SP 72
__global__ __launch_bounds__(256) void attn_kernel(
    const u16* __restrict__ q, const u16* __restrict__ k,
    const u16* __restrict__ vt, u16* __restrict__ out)
{
    __shared__ __align__(16) u16 Ks[64 * SP];
    __shared__ __align__(16) u16 Vs[64 * SP];
    __shared__ __align__(16) u16 Ps[4][32 * SP];  // per-wave P scratch; also Q staging
    const int tid = threadIdx.x, l = tid & 63, w = tid >> 6;
    const int lm = l & 15, quad = l >> 4;
    const int qt = blockIdx.x, bh = blockIdx.y;
    const int b = bh >> 4, h = bh & 15;

    u16* Qstage = &Ps[0][0];
    const u16* qg = q + ((size_t)bh * SEQ + qt * 128) * DH;
#pragma unroll
    for (int j = 0; j < 4; j++) {
        int ch = j * 256 + tid, row = ch >> 3, c8 = ch & 7;
        *(uint4*)(Qstage + row * SP + c8 * 8) = *(const uint4*)(qg + row * DH + c8 * 8);
    }
    __syncthreads();
    bf16x8 aq[2][2];
#pragma unroll
    for (int mi = 0; mi < 2; mi++)
#pragma unroll
        for (int kk = 0; kk < 2; kk++)
            aq[mi][kk] = *(const bf16x8*)(Qstage + (w * 32 + mi * 16 + lm) * SP + kk * 32 + quad * 8);

    floatx4 O[2][4];
#pragma unroll
    for (int mi = 0; mi < 2; mi++)
#pragma unroll
        for (int di = 0; di < 4; di++) O[mi][di] = (floatx4){0.f, 0.f, 0.f, 0.f};
    float mrun[2][4], lrun[2][4];
#pragma unroll
    for (int mi = 0; mi < 2; mi++)
#pragma unroll
        for (int r = 0; r < 4; r++) { mrun[mi][r] = -1e30f; lrun[mi][r] = 0.f; }

    const int prow = tid >> 3, pc = (tid & 7) * 8;
    const u16* kbase = k + (size_t)bh * SEQ * DH;
    const u16* vbase = vt + (size_t)bh * DH * SEQ;
    uint4 kr0, kr1, vr0, vr1;
    {
        kr0 = *(const uint4*)(kbase + (size_t)prow * DH + pc);
        kr1 = *(const uint4*)(kbase + (size_t)(prow + 32) * DH + pc);
        vr0 = *(const uint4*)(vbase + (size_t)prow * SEQ + pc);
        vr1 = *(const uint4*)(vbase + (size_t)(prow + 32) * SEQ + pc);
    }

    for (int t = 0; t < SEQ / 64; t++) {
        __syncthreads();
        *(uint4*)(Ks + prow * SP + pc) = kr0;
        *(uint4*)(Ks + (prow + 32) * SP + pc) = kr1;
        *(uint4*)(Vs + prow * SP + pc) = vr0;
        *(uint4*)(Vs + (prow + 32) * SP + pc) = vr1;
        __syncthreads();
        if (t + 1 < SEQ / 64) {
            const u16* kg = kbase + (size_t)(t + 1) * 64 * DH;
            kr0 = *(const uint4*)(kg + (size_t)prow * DH + pc);
            kr1 = *(const uint4*)(kg + (size_t)(prow + 32) * DH + pc);
            const u16* vg = vbase + (size_t)(t + 1) * 64;
            vr0 = *(const uint4*)(vg + (size_t)prow * SEQ + pc);
            vr1 = *(const uint4*)(vg + (size_t)(prow + 32) * SEQ + pc);
        }

        bf16x8 bk[4][2];
#pragma unroll
        for (int ni = 0; ni < 4; ni++)
#pragma unroll
            for (int kk = 0; kk < 2; kk++)
                bk[ni][kk] = *(const bf16x8*)(Ks + (ni * 16 + lm) * SP + kk * 32 + quad * 8);
        floatx4 Sc[2][4];
#pragma unroll
        for (int mi = 0; mi < 2; mi++)
#pragma unroll
            for (int ni = 0; ni < 4; ni++) {
                floatx4 c = (floatx4){0.f, 0.f, 0.f, 0.f};
                c = __builtin_amdgcn_mfma_f32_16x16x32_bf16(aq[mi][0], bk[ni][0], c, 0, 0, 0);
                c = __builtin_amdgcn_mfma_f32_16x16x32_bf16(aq[mi][1], bk[ni][1], c, 0, 0, 0);
                Sc[mi][ni] = c;
            }

        float alpha[2][4];
#pragma unroll
        for (int mi = 0; mi < 2; mi++)
#pragma unroll
            for (int r = 0; r < 4; r++) {
                float m0 = fmaxf(fmaxf(Sc[mi][0][r], Sc[mi][1][r]),
                                 fmaxf(Sc[mi][2][r], Sc[mi][3][r]));
                m0 = fmaxf(m0, __shfl_xor(m0, 1));
                m0 = fmaxf(m0, __shfl_xor(m0, 2));
                m0 = fmaxf(m0, __shfl_xor(m0, 4));
                m0 = fmaxf(m0, __shfl_xor(m0, 8));
                float mn = fmaxf(mrun[mi][r], m0);
                alpha[mi][r] = exp2f(mrun[mi][r] - mn);
                mrun[mi][r] = mn;
            }
#pragma unroll
        for (int mi = 0; mi < 2; mi++)
#pragma unroll
            for (int ni = 0; ni < 4; ni++)
#pragma unroll
                for (int r = 0; r < 4; r++)
                    Sc[mi][ni][r] = exp2f(Sc[mi][ni][r] - mrun[mi][r]);
#pragma unroll
        for (int mi = 0; mi < 2; mi++)
#pragma unroll
            for (int r = 0; r < 4; r++) {
                float s0 = (Sc[mi][0][r] + Sc[mi][1][r]) + (Sc[mi][2][r] + Sc[mi][3][r]);
                s0 += __shfl_xor(s0, 1);
                s0 += __shfl_xor(s0, 2);
                s0 += __shfl_xor(s0, 4);
                s0 += __shfl_xor(s0, 8);
                lrun[mi][r] = lrun[mi][r] * alpha[mi][r] + s0;
            }
#pragma unroll
        for (int mi = 0; mi < 2; mi++)
#pragma unroll
            for (int di = 0; di < 4; di++)
#pragma unroll
                for (int r = 0; r < 4; r++) O[mi][di][r] *= alpha[mi][r];

        u16* ps = Ps[w];
#pragma unroll
        for (int mi = 0; mi < 2; mi++)
#pragma unroll
            for (int ni = 0; ni < 4; ni++)
#pragma unroll
                for (int r = 0; r < 4; r++)
                    ps[(mi * 16 + quad * 4 + r) * SP + ni * 16 + lm] = f2bf(Sc[mi][ni][r]);
        bf16x8 ap[2][2];
#pragma unroll
        for (int mi = 0; mi < 2; mi++)
#pragma unroll
            for (int kk = 0; kk < 2; kk++)
                ap[mi][kk] = *(const bf16x8*)(ps + (mi * 16 + lm) * SP + kk * 32 + quad * 8);

        bf16x8 bv[4][2];
#pragma unroll
        for (int di = 0; di < 4; di++)
#pragma unroll
            for (int kk = 0; kk < 2; kk++)
                bv[di][kk] = *(const bf16x8*)(Vs + (di * 16 + lm) * SP + kk * 32 + quad * 8);
#pragma unroll
        for (int mi = 0; mi < 2; mi++)
#pragma unroll
            for (int di = 0; di < 4; di++) {
                O[mi][di] = __builtin_amdgcn_mfma_f32_16x16x32_bf16(ap[mi][0], bv[di][0], O[mi][di], 0, 0, 0);
                O[mi][di] = __builtin_amdgcn_mfma_f32_16x16x32_bf16(ap[mi][1], bv[di][1], O[mi][di], 0, 0, 0);
            }
    }

#pragma unroll
    for (int mi = 0; mi < 2; mi++)
#pragma unroll
        for (int di = 0; di < 4; di++)
#pragma unroll
            for (int r = 0; r < 4; r++) {
                int s = qt * 128 + w * 32 + mi * 16 + quad * 4 + r;
                int d = di * 16 + lm;
                float v = O[mi][di][r] / lrun[mi][r];
                out[((size_t)b * SEQ + s) * DMODEL + h * DH + d] = f2bf(v);
            }
}

extern "C" void kernel_launch(void* const* d_in, const int* in_sizes, int n_in,
                              void* d_out, int out_size, void* d_ws, size_t ws_size,
                              hipStream_t stream) {
    (void)in_sizes; (void)n_in; (void)out_size;
    const float* Q  = (const float*)d_in[0];
    const float* K  = (const float*)d_in[1];
    const float* V  = (const float*)d_in[2];
    const float* Wq = (const float*)d_in[3];
    const float* bq = (const float*)d_in[4];
    const float* Wk = (const float*)d_in[5];
    const float* bk = (const float*)d_in[6];
    const float* Wv = (const float*)d_in[7];
    const float* bv = (const float*)d_in[8];
    const float* Wo = (const float*)d_in[9];
    const float* bo = (const float*)d_in[10];

    const size_t NEL = (size_t)2 * NH * SEQ * DH;  // 4,194,304 elements
    u16* base = (u16*)d_ws;
    dim3 bb(256);

    if (ws_size >= 8 * NEL * 2) {
        // full path: 64 MB — everything bf16, pure-glds GEMMs
        u16* Qb   = base;            // 3x input bf16
        u16* Kb   = Qb + NEL;
        u16* Vb   = Kb + NEL;
        u16* Wb   = Vb + NEL;        // 4x 1M weights
        u16* qws  = Wb + NEL;
        u16* kws  = qws + NEL;
        u16* vtws = kws + NEL;
        u16* aws  = vtws + NEL;
        cvt_all<<<dim3(2048, 7), bb, 0, stream>>>(Q, K, V, Wq, Wk, Wv, Wo, Qb, Kb, Vb, Wb);
        gemm_qkv_bb<<<dim3(8, 32, 3), bb, 0, stream>>>(
            Qb, Kb, Vb, Wb, bq, bk, bv, qws, kws, vtws);
        attn_kernel<<<dim3(SEQ / 128, 2 * NH), bb, 0, stream>>>(qws, kws, vtws, aws);
        gemm_o<true><<<dim3(16, 32), bb, 0, stream>>>(aws, Wb + 3145728, bo, (float*)d_out);
    } else if (ws_size >= 5 * NEL * 2) {
        // 42 MB path: bf16 weights only
        u16* Wb = base;
        u16* qws = base + NEL; u16* kws = qws + NEL; u16* vtws = kws + NEL; u16* aws = vtws + NEL;
        cvt_w<<<dim3(512, 4), bb, 0, stream>>>(Wq, Wk, Wv, Wo, Wb);
        gemm_qkv<true><<<dim3(8, 32, 3), bb, 0, stream>>>(
            Q, K, V, Wb, Wb + 1048576, Wb + 2097152, bq, bk, bv, qws, kws, vtws);
        attn_kernel<<<dim3(SEQ / 128, 2 * NH), bb, 0, stream>>>(qws, kws, vtws, aws);
        gemm_o<true><<<dim3(16, 32), bb, 0, stream>>>(aws, Wb + 3145728, bo, (float*)d_out);
    } else {
        u16* qws = base; u16* kws = qws + NEL; u16* vtws = kws + NEL; u16* aws = vtws + NEL;
        gemm_qkv<false><<<dim3(8, 32, 3), bb, 0, stream>>>(
            Q, K, V, Wq, Wk, Wv, bq, bk, bv, qws, kws, vtws);
        attn_kernel<<<dim3(SEQ / 128, 2 * NH), bb, 0, stream>>>(qws, kws, vtws, aws);
        gemm_o<false><<<dim3(16, 32), bb, 0, stream>>>(aws, Wo, bo, (float*)d_out);
    }
}

// Round 6
// 294.859 us; speedup vs baseline: 1.5136x; 1.0422x over previous
//
#include <hip/hip_runtime.h>

#define SEQ 2048
#define DMODEL 1024
#define NH 16
#define DH 64

typedef __attribute__((ext_vector_type(8))) short bf16x8;
typedef __attribute__((ext_vector_type(4))) float floatx4;
typedef unsigned short u16;
typedef unsigned int u32;

typedef const void __attribute__((address_space(1)))* as1cvp;
typedef void __attribute__((address_space(3)))* as3vp;

__device__ __forceinline__ void glds16(const void* g, void* l) {
    __builtin_amdgcn_global_load_lds((as1cvp)g, (as3vp)l, 16, 0, 0);
}

__device__ __forceinline__ u16 f2bf(float f) {
    union { u32 u; float f; } v; v.f = f;
    u32 r = v.u + 0x7fffu + ((v.u >> 16) & 1u);   // RNE
    return (u16)(r >> 16);
}

union Pack8 { u16 h[8]; uint4 q; };

__device__ __forceinline__ uint4 cvt8(const float* __restrict__ p) {
    float4 a = *(const float4*)p;
    float4 b = *(const float4*)(p + 4);
    Pack8 pk;
    pk.h[0] = f2bf(a.x); pk.h[1] = f2bf(a.y); pk.h[2] = f2bf(a.z); pk.h[3] = f2bf(a.w);
    pk.h[4] = f2bf(b.x); pk.h[5] = f2bf(b.y); pk.h[6] = f2bf(b.z); pk.h[7] = f2bf(b.w);
    return pk.q;
}

// q pre-scale: 1/sqrt(Dh); attention uses __expf (v_mul+v_exp — exp2f is the slow
// precise OCML path, measured +15us regression in round 5)
#define QSCALE 0.125f

// ---------------- convert Q,K,V + 4 weights to bf16 once ----------------
__global__ __launch_bounds__(256) void cvt_all(
    const float* __restrict__ Q, const float* __restrict__ K, const float* __restrict__ V,
    const float* __restrict__ W0, const float* __restrict__ W1,
    const float* __restrict__ W2, const float* __restrict__ W3,
    u16* __restrict__ Qb, u16* __restrict__ Kb, u16* __restrict__ Vb,
    u16* __restrict__ Wb)
{
    const int y = blockIdx.y;
    const float* src; u16* dst;
    if (y == 0)      { src = Q;  dst = Qb; }
    else if (y == 1) { src = K;  dst = Kb; }
    else if (y == 2) { src = V;  dst = Vb; }
    else {
        if (blockIdx.x >= 512) return;
        src = (y == 3) ? W0 : (y == 4) ? W1 : (y == 5) ? W2 : W3;
        dst = Wb + (size_t)(y - 3) * 1048576;
    }
    size_t i = ((size_t)blockIdx.x * 256 + threadIdx.x) * 8;
    *(uint4*)(dst + i) = cvt8(src + i);
}

__global__ __launch_bounds__(256) void cvt_w(
    const float* __restrict__ W0, const float* __restrict__ W1,
    const float* __restrict__ W2, const float* __restrict__ W3,
    u16* __restrict__ out)
{
    const float* src = (blockIdx.y == 0) ? W0 : (blockIdx.y == 1) ? W1
                     : (blockIdx.y == 2) ? W2 : W3;
    size_t i = ((size_t)blockIdx.x * 256 + threadIdx.x) * 8;
    *(uint4*)(out + (size_t)blockIdx.y * 1048576 + i) = cvt8(src + i);
}

// ---------------- QKV projection, both operands bf16, pure glds16 staging ----------------
__global__ __launch_bounds__(256) void gemm_qkv_bb(
    const u16* __restrict__ Qb, const u16* __restrict__ Kb, const u16* __restrict__ Vb,
    const u16* __restrict__ Wb,
    const float* __restrict__ b0, const float* __restrict__ b1, const float* __restrict__ b2,
    u16* __restrict__ qo, u16* __restrict__ ko, u16* __restrict__ vto)
{
    __shared__ __align__(16) u16 As[128 * 32];
    __shared__ __align__(16) u16 Bs[128 * 32];
    const int tid = threadIdx.x, l = tid & 63, w = tid >> 6;
    const int lm = l & 15, quad = l >> 4;
    const int wr = (w >> 1) * 64, wc = (w & 1) * 64;
    const int bm = blockIdx.y * 128, bn = blockIdx.x * 128;
    const int z = blockIdx.z;
    const u16* A      = (z == 0) ? Qb : (z == 1) ? Kb : Vb;
    const u16* W      = Wb + (size_t)z * 1048576;
    const float* bias = (z == 0) ? b0 : (z == 1) ? b1 : b2;

    const int srow = tid >> 2, scol = (tid & 3) * 8;

    floatx4 acc[4][4];
#pragma unroll
    for (int i = 0; i < 4; i++)
#pragma unroll
        for (int j = 0; j < 4; j++) acc[i][j] = (floatx4){0.f, 0.f, 0.f, 0.f};

    for (int kt = 0; kt < DMODEL; kt += 32) {
        __syncthreads();
        glds16(A + (size_t)(bm + srow) * DMODEL + kt + scol, As + w * 512);
        glds16(A + (size_t)(bm + 64 + srow) * DMODEL + kt + scol, As + 2048 + w * 512);
        glds16(W + (size_t)(bn + srow) * DMODEL + kt + scol, Bs + w * 512);
        glds16(W + (size_t)(bn + 64 + srow) * DMODEL + kt + scol, Bs + 2048 + w * 512);
        __syncthreads();

        bf16x8 af[4], bfr[4];
#pragma unroll
        for (int mi = 0; mi < 4; mi++)
            af[mi] = *(const bf16x8*)(As + (wr + mi * 16 + lm) * 32 + quad * 8);
#pragma unroll
        for (int ni = 0; ni < 4; ni++)
            bfr[ni] = *(const bf16x8*)(Bs + (wc + ni * 16 + lm) * 32 + quad * 8);
#pragma unroll
        for (int mi = 0; mi < 4; mi++)
#pragma unroll
            for (int ni = 0; ni < 4; ni++)
                acc[mi][ni] = __builtin_amdgcn_mfma_f32_16x16x32_bf16(
                    af[mi], bfr[ni], acc[mi][ni], 0, 0, 0);
    }

    const float sc = (z == 0) ? QSCALE : 1.0f;
    u16* outp = (z == 0) ? qo : (z == 1) ? ko : vto;
#pragma unroll
    for (int ni = 0; ni < 4; ni++) {
        int col = bn + wc + ni * 16 + lm;
        float bv = bias[col];
#pragma unroll
        for (int mi = 0; mi < 4; mi++) {
#pragma unroll
            for (int r = 0; r < 4; r++) {
                int rowg = bm + wr + mi * 16 + quad * 4 + r;
                float v = (acc[mi][ni][r] + bv) * sc;
                int b = rowg >> 11, s = rowg & 2047, h = col >> 6, d = col & 63;
                if (z < 2)
                    outp[((size_t)(b * NH + h) * SEQ + s) * DH + d] = f2bf(v);
                else
                    outp[((size_t)(b * NH + h) * DH + d) * SEQ + s] = f2bf(v);
            }
        }
    }
}

// ---------------- legacy QKV (A f32 converted in staging) ----------------
template<bool WBF>
__global__ __launch_bounds__(256) void gemm_qkv(
    const float* __restrict__ Qf, const float* __restrict__ Kf, const float* __restrict__ Vf,
    const void* __restrict__ W0, const void* __restrict__ W1, const void* __restrict__ W2,
    const float* __restrict__ b0, const float* __restrict__ b1, const float* __restrict__ b2,
    u16* __restrict__ qo, u16* __restrict__ ko, u16* __restrict__ vto)
{
    __shared__ __align__(16) u16 As[128 * 32];
    __shared__ __align__(16) u16 Bs[128 * 32];
    const int tid = threadIdx.x, l = tid & 63, w = tid >> 6;
    const int lm = l & 15, quad = l >> 4;
    const int wr = (w >> 1) * 64, wc = (w & 1) * 64;
    const int bm = blockIdx.y * 128, bn = blockIdx.x * 128;
    const int z = blockIdx.z;
    const float* A    = (z == 0) ? Qf : (z == 1) ? Kf : Vf;
    const void* Wp    = (z == 0) ? W0 : (z == 1) ? W1 : W2;
    const float* bias = (z == 0) ? b0 : (z == 1) ? b1 : b2;

    floatx4 acc[4][4];
#pragma unroll
    for (int i = 0; i < 4; i++)
#pragma unroll
        for (int j = 0; j < 4; j++) acc[i][j] = (floatx4){0.f, 0.f, 0.f, 0.f};

    for (int kt = 0; kt < DMODEL; kt += 32) {
        __syncthreads();
#pragma unroll
        for (int j = 0; j < 2; j++) {
            int ch = j * 256 + tid, row = ch >> 2, c = ch & 3;
            *(uint4*)(As + ch * 8) = cvt8(A + (size_t)(bm + row) * DMODEL + kt + c * 8);
        }
        if (WBF) {
            const u16* Wb = (const u16*)Wp;
            glds16(Wb + (size_t)(bn + (tid >> 2)) * DMODEL + kt + (tid & 3) * 8, Bs + w * 512);
            glds16(Wb + (size_t)(bn + 64 + (tid >> 2)) * DMODEL + kt + (tid & 3) * 8, Bs + 2048 + w * 512);
        } else {
            const float* Wf = (const float*)Wp;
#pragma unroll
            for (int j = 0; j < 2; j++) {
                int ch = j * 256 + tid, row = ch >> 2, c = ch & 3;
                *(uint4*)(Bs + ch * 8) = cvt8(Wf + (size_t)(bn + row) * DMODEL + kt + c * 8);
            }
        }
        __syncthreads();

        bf16x8 af[4], bfr[4];
#pragma unroll
        for (int mi = 0; mi < 4; mi++)
            af[mi] = *(const bf16x8*)(As + (wr + mi * 16 + lm) * 32 + quad * 8);
#pragma unroll
        for (int ni = 0; ni < 4; ni++)
            bfr[ni] = *(const bf16x8*)(Bs + (wc + ni * 16 + lm) * 32 + quad * 8);
#pragma unroll
        for (int mi = 0; mi < 4; mi++)
#pragma unroll
            for (int ni = 0; ni < 4; ni++)
                acc[mi][ni] = __builtin_amdgcn_mfma_f32_16x16x32_bf16(
                    af[mi], bfr[ni], acc[mi][ni], 0, 0, 0);
    }

    const float sc = (z == 0) ? QSCALE : 1.0f;
    u16* outp = (z == 0) ? qo : (z == 1) ? ko : vto;
#pragma unroll
    for (int ni = 0; ni < 4; ni++) {
        int col = bn + wc + ni * 16 + lm;
        float bv = bias[col];
#pragma unroll
        for (int mi = 0; mi < 4; mi++) {
#pragma unroll
            for (int r = 0; r < 4; r++) {
                int rowg = bm + wr + mi * 16 + quad * 4 + r;
                float v = (acc[mi][ni][r] + bv) * sc;
                int b = rowg >> 11, s = rowg & 2047, h = col >> 6, d = col & 63;
                if (z < 2)
                    outp[((size_t)(b * NH + h) * SEQ + s) * DH + d] = f2bf(v);
                else
                    outp[((size_t)(b * NH + h) * DH + d) * SEQ + s] = f2bf(v);
            }
        }
    }
}

// ---------------- O-projection: A bf16, W bf16/f32, out f32. 128x64 tiles ----------------
template<bool WBF>
__global__ __launch_bounds__(256) void gemm_o(
    const u16* __restrict__ A, const void* __restrict__ Wp,
    const float* __restrict__ bias, float* __restrict__ out)
{
    __shared__ __align__(16) u16 As[128 * 32];
    __shared__ __align__(16) u16 Bs[64 * 32];
    const int tid = threadIdx.x, l = tid & 63, w = tid >> 6;
    const int lm = l & 15, quad = l >> 4;
    const int bm = blockIdx.y * 128, bn = blockIdx.x * 64;

    floatx4 acc[2][4];
#pragma unroll
    for (int i = 0; i < 2; i++)
#pragma unroll
        for (int j = 0; j < 4; j++) acc[i][j] = (floatx4){0.f, 0.f, 0.f, 0.f};

    for (int kt = 0; kt < DMODEL; kt += 32) {
        __syncthreads();
        glds16(A + (size_t)(bm + (tid >> 2)) * DMODEL + kt + (tid & 3) * 8, As + w * 512);
        glds16(A + (size_t)(bm + 64 + (tid >> 2)) * DMODEL + kt + (tid & 3) * 8, As + 2048 + w * 512);
        if (WBF) {
            glds16((const u16*)Wp + (size_t)(bn + (tid >> 2)) * DMODEL + kt + (tid & 3) * 8, Bs + w * 512);
        } else {
            *(uint4*)(Bs + tid * 8) =
                cvt8((const float*)Wp + (size_t)(bn + (tid >> 2)) * DMODEL + kt + (tid & 3) * 8);
        }
        __syncthreads();

        bf16x8 af[2], bfr[4];
#pragma unroll
        for (int mi = 0; mi < 2; mi++)
            af[mi] = *(const bf16x8*)(As + (w * 32 + mi * 16 + lm) * 32 + quad * 8);
#pragma unroll
        for (int ni = 0; ni < 4; ni++)
            bfr[ni] = *(const bf16x8*)(Bs + (ni * 16 + lm) * 32 + quad * 8);
#pragma unroll
        for (int mi = 0; mi < 2; mi++)
#pragma unroll
            for (int ni = 0; ni < 4; ni++)
                acc[mi][ni] = __builtin_amdgcn_mfma_f32_16x16x32_bf16(
                    af[mi], bfr[ni], acc[mi][ni], 0, 0, 0);
    }

#pragma unroll
    for (int ni = 0; ni < 4; ni++) {
        int col = bn + ni * 16 + lm;
        float bv = bias[col];
#pragma unroll
        for (int mi = 0; mi < 2; mi++) {
#pragma unroll
            for (int r = 0; r < 4; r++) {
                int rowg = bm + w * 32 + mi * 16 + quad * 4 + r;
                out[(size_t)rowg * DMODEL + col] = acc[mi][ni][r] + bv;
            }
        }
    }
}

// ---------------- Flash attention v3: 128-key softmax pass ----------------
// grid (SEQ/128, B*NH), 4 waves; wave w owns q-rows w*32..w*32+31.
// Ks [key(128)][d(64)] stride SP; Vs [d(64)][key(128)] stride SPV; Ps per-wave [qrow(32)][key(128)].
#define SP 72
#define SPV 136
__global__ __launch_bounds__(256, 2) void attn_kernel(
    const u16* __restrict__ q, const u16* __restrict__ k,
    const u16* __restrict__ vt, u16* __restrict__ out)
{
    __shared__ __align__(16) u16 Ks[128 * SP];
    __shared__ __align__(16) u16 Vs[64 * SPV];
    __shared__ __align__(16) u16 Ps[4][32 * SPV];  // per-wave P scratch; also Q staging
    const int tid = threadIdx.x, l = tid & 63, w = tid >> 6;
    const int lm = l & 15, quad = l >> 4;
    const int qt = blockIdx.x, bh = blockIdx.y;
    const int b = bh >> 4, h = bh & 15;

    // stage Q tile 128x64 into Ps region at stride SPV (4*32*SPV == 128*SPV exactly)
    u16* Qstage = &Ps[0][0];
    const u16* qg = q + ((size_t)bh * SEQ + qt * 128) * DH;
#pragma unroll
    for (int j = 0; j < 4; j++) {
        int ch = j * 256 + tid, row = ch >> 3, c8 = ch & 7;
        *(uint4*)(Qstage + row * SPV + c8 * 8) = *(const uint4*)(qg + row * DH + c8 * 8);
    }
    __syncthreads();
    bf16x8 aq[2][2];   // wave w's q rows live exactly in Ps[w]
#pragma unroll
    for (int mi = 0; mi < 2; mi++)
#pragma unroll
        for (int kk = 0; kk < 2; kk++)
            aq[mi][kk] = *(const bf16x8*)(Qstage + (w * 32 + mi * 16 + lm) * SPV + kk * 32 + quad * 8);

    floatx4 O[2][4];
#pragma unroll
    for (int mi = 0; mi < 2; mi++)
#pragma unroll
        for (int di = 0; di < 4; di++) O[mi][di] = (floatx4){0.f, 0.f, 0.f, 0.f};
    float mrun[2][4], lrun[2][4];
#pragma unroll
    for (int mi = 0; mi < 2; mi++)
#pragma unroll
        for (int r = 0; r < 4; r++) { mrun[mi][r] = -1e30f; lrun[mi][r] = 0.f; }

    const int krow = tid >> 3, kcol = (tid & 7) * 8;     // K stage: 32 rows x 8 chunks
    const int vrow = tid >> 4, vcol = (tid & 15) * 8;    // V stage: 16 rows x 16 chunks
    const u16* kbase = k + (size_t)bh * SEQ * DH;
    const u16* vbase = vt + (size_t)bh * DH * SEQ;
    uint4 kr[4], vr[4];
#pragma unroll
    for (int j = 0; j < 4; j++) {
        kr[j] = *(const uint4*)(kbase + (size_t)(krow + 32 * j) * DH + kcol);
        vr[j] = *(const uint4*)(vbase + (size_t)(vrow + 16 * j) * SEQ + vcol);
    }

    for (int t = 0; t < SEQ / 128; t++) {
        __syncthreads();
#pragma unroll
        for (int j = 0; j < 4; j++) {
            *(uint4*)(Ks + (krow + 32 * j) * SP + kcol) = kr[j];
            *(uint4*)(Vs + (vrow + 16 * j) * SPV + vcol) = vr[j];
        }
        __syncthreads();
        if (t + 1 < SEQ / 128) {
            const u16* kg = kbase + (size_t)(t + 1) * 128 * DH;
            const u16* vg = vbase + (size_t)(t + 1) * 128;
#pragma unroll
            for (int j = 0; j < 4; j++) {
                kr[j] = *(const uint4*)(kg + (size_t)(krow + 32 * j) * DH + kcol);
                vr[j] = *(const uint4*)(vg + (size_t)(vrow + 16 * j) * SEQ + vcol);
            }
        }

        // S = q k^T : ni outer (bk read once, used by both mi)
        floatx4 Sc[2][8];
#pragma unroll
        for (int ni = 0; ni < 8; ni++) {
            bf16x8 bk0 = *(const bf16x8*)(Ks + (ni * 16 + lm) * SP + quad * 8);
            bf16x8 bk1 = *(const bf16x8*)(Ks + (ni * 16 + lm) * SP + 32 + quad * 8);
#pragma unroll
            for (int mi = 0; mi < 2; mi++) {
                floatx4 c = (floatx4){0.f, 0.f, 0.f, 0.f};
                c = __builtin_amdgcn_mfma_f32_16x16x32_bf16(aq[mi][0], bk0, c, 0, 0, 0);
                c = __builtin_amdgcn_mfma_f32_16x16x32_bf16(aq[mi][1], bk1, c, 0, 0, 0);
                Sc[mi][ni] = c;
            }
        }

        // online softmax over 128 keys at once
        float alpha[2][4];
#pragma unroll
        for (int mi = 0; mi < 2; mi++)
#pragma unroll
            for (int r = 0; r < 4; r++) {
                float m0 = fmaxf(fmaxf(fmaxf(Sc[mi][0][r], Sc[mi][1][r]),
                                       fmaxf(Sc[mi][2][r], Sc[mi][3][r])),
                                 fmaxf(fmaxf(Sc[mi][4][r], Sc[mi][5][r]),
                                       fmaxf(Sc[mi][6][r], Sc[mi][7][r])));
                m0 = fmaxf(m0, __shfl_xor(m0, 1));
                m0 = fmaxf(m0, __shfl_xor(m0, 2));
                m0 = fmaxf(m0, __shfl_xor(m0, 4));
                m0 = fmaxf(m0, __shfl_xor(m0, 8));
                float mn = fmaxf(mrun[mi][r], m0);
                alpha[mi][r] = __expf(mrun[mi][r] - mn);
                mrun[mi][r] = mn;
            }
#pragma unroll
        for (int mi = 0; mi < 2; mi++)
#pragma unroll
            for (int ni = 0; ni < 8; ni++)
#pragma unroll
                for (int r = 0; r < 4; r++)
                    Sc[mi][ni][r] = __expf(Sc[mi][ni][r] - mrun[mi][r]);
#pragma unroll
        for (int mi = 0; mi < 2; mi++)
#pragma unroll
            for (int r = 0; r < 4; r++) {
                float s0 = ((Sc[mi][0][r] + Sc[mi][1][r]) + (Sc[mi][2][r] + Sc[mi][3][r]))
                         + ((Sc[mi][4][r] + Sc[mi][5][r]) + (Sc[mi][6][r] + Sc[mi][7][r]));
                s0 += __shfl_xor(s0, 1);
                s0 += __shfl_xor(s0, 2);
                s0 += __shfl_xor(s0, 4);
                s0 += __shfl_xor(s0, 8);
                lrun[mi][r] = lrun[mi][r] * alpha[mi][r] + s0;
            }
#pragma unroll
        for (int mi = 0; mi < 2; mi++)
#pragma unroll
            for (int di = 0; di < 4; di++)
#pragma unroll
                for (int r = 0; r < 4; r++) O[mi][di][r] *= alpha[mi][r];

        // P: C-layout -> A-layout via per-wave scratch (same-wave ordering, no barrier)
        u16* ps = Ps[w];
#pragma unroll
        for (int mi = 0; mi < 2; mi++)
#pragma unroll
            for (int ni = 0; ni < 8; ni++)
#pragma unroll
                for (int r = 0; r < 4; r++)
                    ps[(mi * 16 + quad * 4 + r) * SPV + ni * 16 + lm] = f2bf(Sc[mi][ni][r]);

        // O += P @ V : kk outer, bv read once per (kk,di), shared across mi
#pragma unroll
        for (int kk = 0; kk < 4; kk++) {
            bf16x8 ap0 = *(const bf16x8*)(ps + (lm) * SPV + kk * 32 + quad * 8);
            bf16x8 ap1 = *(const bf16x8*)(ps + (16 + lm) * SPV + kk * 32 + quad * 8);
#pragma unroll
            for (int di = 0; di < 4; di++) {
                bf16x8 bvv = *(const bf16x8*)(Vs + (di * 16 + lm) * SPV + kk * 32 + quad * 8);
                O[0][di] = __builtin_amdgcn_mfma_f32_16x16x32_bf16(ap0, bvv, O[0][di], 0, 0, 0);
                O[1][di] = __builtin_amdgcn_mfma_f32_16x16x32_bf16(ap1, bvv, O[1][di], 0, 0, 0);
            }
        }
    }

    // epilogue
#pragma unroll
    for (int mi = 0; mi < 2; mi++) {
        float inv[4];
#pragma unroll
        for (int r = 0; r < 4; r++) inv[r] = 1.0f / lrun[mi][r];
#pragma unroll
        for (int di = 0; di < 4; di++)
#pragma unroll
            for (int r = 0; r < 4; r++) {
                int s = qt * 128 + w * 32 + mi * 16 + quad * 4 + r;
                int d = di * 16 + lm;
                out[((size_t)b * SEQ + s) * DMODEL + h * DH + d] = f2bf(O[mi][di][r] * inv[r]);
            }
    }
}

extern "C" void kernel_launch(void* const* d_in, const int* in_sizes, int n_in,
                              void* d_out, int out_size, void* d_ws, size_t ws_size,
                              hipStream_t stream) {
    (void)in_sizes; (void)n_in; (void)out_size;
    const float* Q  = (const float*)d_in[0];
    const float* K  = (const float*)d_in[1];
    const float* V  = (const float*)d_in[2];
    const float* Wq = (const float*)d_in[3];
    const float* bq = (const float*)d_in[4];
    const float* Wk = (const float*)d_in[5];
    const float* bk = (const float*)d_in[6];
    const float* Wv = (const float*)d_in[7];
    const float* bv = (const float*)d_in[8];
    const float* Wo = (const float*)d_in[9];
    const float* bo = (const float*)d_in[10];

    const size_t NEL = (size_t)2 * NH * SEQ * DH;  // 4,194,304 elements
    u16* base = (u16*)d_ws;
    dim3 bb(256);

    if (ws_size >= 8 * NEL * 2) {
        u16* Qb   = base;
        u16* Kb   = Qb + NEL;
        u16* Vb   = Kb + NEL;
        u16* Wb   = Vb + NEL;
        u16* qws  = Wb + NEL;
        u16* kws  = qws + NEL;
        u16* vtws = kws + NEL;
        u16* aws  = vtws + NEL;
        cvt_all<<<dim3(2048, 7), bb, 0, stream>>>(Q, K, V, Wq, Wk, Wv, Wo, Qb, Kb, Vb, Wb);
        gemm_qkv_bb<<<dim3(8, 32, 3), bb, 0, stream>>>(
            Qb, Kb, Vb, Wb, bq, bk, bv, qws, kws, vtws);
        attn_kernel<<<dim3(SEQ / 128, 2 * NH), bb, 0, stream>>>(qws, kws, vtws, aws);
        gemm_o<true><<<dim3(16, 32), bb, 0, stream>>>(aws, Wb + 3145728, bo, (float*)d_out);
    } else if (ws_size >= 5 * NEL * 2) {
        u16* Wb = base;
        u16* qws = base + NEL; u16* kws = qws + NEL; u16* vtws = kws + NEL; u16* aws = vtws + NEL;
        cvt_w<<<dim3(512, 4), bb, 0, stream>>>(Wq, Wk, Wv, Wo, Wb);
        gemm_qkv<true><<<dim3(8, 32, 3), bb, 0, stream>>>(
            Q, K, V, Wb, Wb + 1048576, Wb + 2097152, bq, bk, bv, qws, kws, vtws);
        attn_kernel<<<dim3(SEQ / 128, 2 * NH), bb, 0, stream>>>(qws, kws, vtws, aws);
        gemm_o<true><<<dim3(16, 32), bb, 0, stream>>>(aws, Wb + 3145728, bo, (float*)d_out);
    } else {
        u16* qws = base; u16* kws = qws + NEL; u16* vtws = kws + NEL; u16* aws = vtws + NEL;
        gemm_qkv<false><<<dim3(8, 32, 3), bb, 0, stream>>>(
            Q, K, V, Wq, Wk, Wv, bq, bk, bv, qws, kws, vtws);
        attn_kernel<<<dim3(SEQ / 128, 2 * NH), bb, 0, stream>>>(qws, kws, vtws, aws);
        gemm_o<false><<<dim3(16, 32), bb, 0, stream>>>(aws, Wo, bo, (float*)d_out);
    }
}

// Round 7
// 252.842 us; speedup vs baseline: 1.7652x; 1.1662x over previous
//
#include <hip/hip_runtime.h>

#define SEQ 2048
#define DMODEL 1024
#define NH 16
#define DH 64

typedef __attribute__((ext_vector_type(8))) short bf16x8;
typedef __attribute__((ext_vector_type(4))) short bf16x4;
typedef __attribute__((ext_vector_type(4))) float floatx4;
typedef __attribute__((ext_vector_type(4))) unsigned short u16x4;
typedef unsigned short u16;
typedef unsigned int u32;

typedef const void __attribute__((address_space(1)))* as1cvp;
typedef void __attribute__((address_space(3)))* as3vp;

__device__ __forceinline__ void glds16(const void* g, void* l) {
    __builtin_amdgcn_global_load_lds((as1cvp)g, (as3vp)l, 16, 0, 0);
}

__device__ __forceinline__ u16 f2bf(float f) {
    union { u32 u; float f; } v; v.f = f;
    u32 r = v.u + 0x7fffu + ((v.u >> 16) & 1u);   // RNE
    return (u16)(r >> 16);
}

// 16x16x16 bf16 MFMA (2-VGPR A/B frags): B-frag layout k=quad*4+j matches the
// C-layout of S^T, letting P feed PV straight from registers (no LDS transpose).
__device__ __forceinline__ floatx4 mfma16(bf16x4 a, bf16x4 b, floatx4 c) {
#if __has_builtin(__builtin_amdgcn_mfma_f32_16x16x16bf16_1k)
    return __builtin_amdgcn_mfma_f32_16x16x16bf16_1k(a, b, c, 0, 0, 0);
#else
    asm volatile("v_mfma_f32_16x16x16_bf16 %0, %1, %2, %0" : "+v"(c) : "v"(a), "v"(b));
    return c;
#endif
}

union Pack8 { u16 h[8]; uint4 q; };

__device__ __forceinline__ uint4 cvt8(const float* __restrict__ p) {
    float4 a = *(const float4*)p;
    float4 b = *(const float4*)(p + 4);
    Pack8 pk;
    pk.h[0] = f2bf(a.x); pk.h[1] = f2bf(a.y); pk.h[2] = f2bf(a.z); pk.h[3] = f2bf(a.w);
    pk.h[4] = f2bf(b.x); pk.h[5] = f2bf(b.y); pk.h[6] = f2bf(b.z); pk.h[7] = f2bf(b.w);
    return pk.q;
}

// q pre-scale: 1/sqrt(Dh); __expf only (exp2f = slow OCML path, r5 regression)
#define QSCALE 0.125f

// ---------------- convert Q,K,V + 4 weights to bf16 once ----------------
__global__ __launch_bounds__(256) void cvt_all(
    const float* __restrict__ Q, const float* __restrict__ K, const float* __restrict__ V,
    const float* __restrict__ W0, const float* __restrict__ W1,
    const float* __restrict__ W2, const float* __restrict__ W3,
    u16* __restrict__ Qb, u16* __restrict__ Kb, u16* __restrict__ Vb,
    u16* __restrict__ Wb)
{
    const int y = blockIdx.y;
    const float* src; u16* dst;
    if (y == 0)      { src = Q;  dst = Qb; }
    else if (y == 1) { src = K;  dst = Kb; }
    else if (y == 2) { src = V;  dst = Vb; }
    else {
        if (blockIdx.x >= 512) return;
        src = (y == 3) ? W0 : (y == 4) ? W1 : (y == 5) ? W2 : W3;
        dst = Wb + (size_t)(y - 3) * 1048576;
    }
    size_t i = ((size_t)blockIdx.x * 256 + threadIdx.x) * 8;
    *(uint4*)(dst + i) = cvt8(src + i);
}

__global__ __launch_bounds__(256) void cvt_w(
    const float* __restrict__ W0, const float* __restrict__ W1,
    const float* __restrict__ W2, const float* __restrict__ W3,
    u16* __restrict__ out)
{
    const float* src = (blockIdx.y == 0) ? W0 : (blockIdx.y == 1) ? W1
                     : (blockIdx.y == 2) ? W2 : W3;
    size_t i = ((size_t)blockIdx.x * 256 + threadIdx.x) * 8;
    *(uint4*)(out + (size_t)blockIdx.y * 1048576 + i) = cvt8(src + i);
}

// ---------------- QKV projection, both operands bf16, pure glds16 staging ----------------
__global__ __launch_bounds__(256) void gemm_qkv_bb(
    const u16* __restrict__ Qb, const u16* __restrict__ Kb, const u16* __restrict__ Vb,
    const u16* __restrict__ Wb,
    const float* __restrict__ b0, const float* __restrict__ b1, const float* __restrict__ b2,
    u16* __restrict__ qo, u16* __restrict__ ko, u16* __restrict__ vto)
{
    __shared__ __align__(16) u16 As[128 * 32];
    __shared__ __align__(16) u16 Bs[128 * 32];
    const int tid = threadIdx.x, l = tid & 63, w = tid >> 6;
    const int lm = l & 15, quad = l >> 4;
    const int wr = (w >> 1) * 64, wc = (w & 1) * 64;
    const int bm = blockIdx.y * 128, bn = blockIdx.x * 128;
    const int z = blockIdx.z;
    const u16* A      = (z == 0) ? Qb : (z == 1) ? Kb : Vb;
    const u16* W      = Wb + (size_t)z * 1048576;
    const float* bias = (z == 0) ? b0 : (z == 1) ? b1 : b2;

    const int srow = tid >> 2, scol = (tid & 3) * 8;

    floatx4 acc[4][4];
#pragma unroll
    for (int i = 0; i < 4; i++)
#pragma unroll
        for (int j = 0; j < 4; j++) acc[i][j] = (floatx4){0.f, 0.f, 0.f, 0.f};

    for (int kt = 0; kt < DMODEL; kt += 32) {
        __syncthreads();
        glds16(A + (size_t)(bm + srow) * DMODEL + kt + scol, As + w * 512);
        glds16(A + (size_t)(bm + 64 + srow) * DMODEL + kt + scol, As + 2048 + w * 512);
        glds16(W + (size_t)(bn + srow) * DMODEL + kt + scol, Bs + w * 512);
        glds16(W + (size_t)(bn + 64 + srow) * DMODEL + kt + scol, Bs + 2048 + w * 512);
        __syncthreads();

        bf16x8 af[4], bfr[4];
#pragma unroll
        for (int mi = 0; mi < 4; mi++)
            af[mi] = *(const bf16x8*)(As + (wr + mi * 16 + lm) * 32 + quad * 8);
#pragma unroll
        for (int ni = 0; ni < 4; ni++)
            bfr[ni] = *(const bf16x8*)(Bs + (wc + ni * 16 + lm) * 32 + quad * 8);
#pragma unroll
        for (int mi = 0; mi < 4; mi++)
#pragma unroll
            for (int ni = 0; ni < 4; ni++)
                acc[mi][ni] = __builtin_amdgcn_mfma_f32_16x16x32_bf16(
                    af[mi], bfr[ni], acc[mi][ni], 0, 0, 0);
    }

    const float sc = (z == 0) ? QSCALE : 1.0f;
    u16* outp = (z == 0) ? qo : (z == 1) ? ko : vto;
#pragma unroll
    for (int ni = 0; ni < 4; ni++) {
        int col = bn + wc + ni * 16 + lm;
        float bv = bias[col];
#pragma unroll
        for (int mi = 0; mi < 4; mi++) {
#pragma unroll
            for (int r = 0; r < 4; r++) {
                int rowg = bm + wr + mi * 16 + quad * 4 + r;
                float v = (acc[mi][ni][r] + bv) * sc;
                int b = rowg >> 11, s = rowg & 2047, h = col >> 6, d = col & 63;
                if (z < 2)
                    outp[((size_t)(b * NH + h) * SEQ + s) * DH + d] = f2bf(v);
                else
                    outp[((size_t)(b * NH + h) * DH + d) * SEQ + s] = f2bf(v);
            }
        }
    }
}

// ---------------- legacy QKV (A f32 converted in staging) ----------------
template<bool WBF>
__global__ __launch_bounds__(256) void gemm_qkv(
    const float* __restrict__ Qf, const float* __restrict__ Kf, const float* __restrict__ Vf,
    const void* __restrict__ W0, const void* __restrict__ W1, const void* __restrict__ W2,
    const float* __restrict__ b0, const float* __restrict__ b1, const float* __restrict__ b2,
    u16* __restrict__ qo, u16* __restrict__ ko, u16* __restrict__ vto)
{
    __shared__ __align__(16) u16 As[128 * 32];
    __shared__ __align__(16) u16 Bs[128 * 32];
    const int tid = threadIdx.x, l = tid & 63, w = tid >> 6;
    const int lm = l & 15, quad = l >> 4;
    const int wr = (w >> 1) * 64, wc = (w & 1) * 64;
    const int bm = blockIdx.y * 128, bn = blockIdx.x * 128;
    const int z = blockIdx.z;
    const float* A    = (z == 0) ? Qf : (z == 1) ? Kf : Vf;
    const void* Wp    = (z == 0) ? W0 : (z == 1) ? W1 : W2;
    const float* bias = (z == 0) ? b0 : (z == 1) ? b1 : b2;

    floatx4 acc[4][4];
#pragma unroll
    for (int i = 0; i < 4; i++)
#pragma unroll
        for (int j = 0; j < 4; j++) acc[i][j] = (floatx4){0.f, 0.f, 0.f, 0.f};

    for (int kt = 0; kt < DMODEL; kt += 32) {
        __syncthreads();
#pragma unroll
        for (int j = 0; j < 2; j++) {
            int ch = j * 256 + tid, row = ch >> 2, c = ch & 3;
            *(uint4*)(As + ch * 8) = cvt8(A + (size_t)(bm + row) * DMODEL + kt + c * 8);
        }
        if (WBF) {
            const u16* Wb = (const u16*)Wp;
            glds16(Wb + (size_t)(bn + (tid >> 2)) * DMODEL + kt + (tid & 3) * 8, Bs + w * 512);
            glds16(Wb + (size_t)(bn + 64 + (tid >> 2)) * DMODEL + kt + (tid & 3) * 8, Bs + 2048 + w * 512);
        } else {
            const float* Wf = (const float*)Wp;
#pragma unroll
            for (int j = 0; j < 2; j++) {
                int ch = j * 256 + tid, row = ch >> 2, c = ch & 3;
                *(uint4*)(Bs + ch * 8) = cvt8(Wf + (size_t)(bn + row) * DMODEL + kt + c * 8);
            }
        }
        __syncthreads();

        bf16x8 af[4], bfr[4];
#pragma unroll
        for (int mi = 0; mi < 4; mi++)
            af[mi] = *(const bf16x8*)(As + (wr + mi * 16 + lm) * 32 + quad * 8);
#pragma unroll
        for (int ni = 0; ni < 4; ni++)
            bfr[ni] = *(const bf16x8*)(Bs + (wc + ni * 16 + lm) * 32 + quad * 8);
#pragma unroll
        for (int mi = 0; mi < 4; mi++)
#pragma unroll
            for (int ni = 0; ni < 4; ni++)
                acc[mi][ni] = __builtin_amdgcn_mfma_f32_16x16x32_bf16(
                    af[mi], bfr[ni], acc[mi][ni], 0, 0, 0);
    }

    const float sc = (z == 0) ? QSCALE : 1.0f;
    u16* outp = (z == 0) ? qo : (z == 1) ? ko : vto;
#pragma unroll
    for (int ni = 0; ni < 4; ni++) {
        int col = bn + wc + ni * 16 + lm;
        float bv = bias[col];
#pragma unroll
        for (int mi = 0; mi < 4; mi++) {
#pragma unroll
            for (int r = 0; r < 4; r++) {
                int rowg = bm + wr + mi * 16 + quad * 4 + r;
                float v = (acc[mi][ni][r] + bv) * sc;
                int b = rowg >> 11, s = rowg & 2047, h = col >> 6, d = col & 63;
                if (z < 2)
                    outp[((size_t)(b * NH + h) * SEQ + s) * DH + d] = f2bf(v);
                else
                    outp[((size_t)(b * NH + h) * DH + d) * SEQ + s] = f2bf(v);
            }
        }
    }
}

// ---------------- O-projection: A bf16, W bf16/f32, out f32. 128x64 tiles ----------------
template<bool WBF>
__global__ __launch_bounds__(256) void gemm_o(
    const u16* __restrict__ A, const void* __restrict__ Wp,
    const float* __restrict__ bias, float* __restrict__ out)
{
    __shared__ __align__(16) u16 As[128 * 32];
    __shared__ __align__(16) u16 Bs[64 * 32];
    const int tid = threadIdx.x, l = tid & 63, w = tid >> 6;
    const int lm = l & 15, quad = l >> 4;
    const int bm = blockIdx.y * 128, bn = blockIdx.x * 64;

    floatx4 acc[2][4];
#pragma unroll
    for (int i = 0; i < 2; i++)
#pragma unroll
        for (int j = 0; j < 4; j++) acc[i][j] = (floatx4){0.f, 0.f, 0.f, 0.f};

    for (int kt = 0; kt < DMODEL; kt += 32) {
        __syncthreads();
        glds16(A + (size_t)(bm + (tid >> 2)) * DMODEL + kt + (tid & 3) * 8, As + w * 512);
        glds16(A + (size_t)(bm + 64 + (tid >> 2)) * DMODEL + kt + (tid & 3) * 8, As + 2048 + w * 512);
        if (WBF) {
            glds16((const u16*)Wp + (size_t)(bn + (tid >> 2)) * DMODEL + kt + (tid & 3) * 8, Bs + w * 512);
        } else {
            *(uint4*)(Bs + tid * 8) =
                cvt8((const float*)Wp + (size_t)(bn + (tid >> 2)) * DMODEL + kt + (tid & 3) * 8);
        }
        __syncthreads();

        bf16x8 af[2], bfr[4];
#pragma unroll
        for (int mi = 0; mi < 2; mi++)
            af[mi] = *(const bf16x8*)(As + (w * 32 + mi * 16 + lm) * 32 + quad * 8);
#pragma unroll
        for (int ni = 0; ni < 4; ni++)
            bfr[ni] = *(const bf16x8*)(Bs + (ni * 16 + lm) * 32 + quad * 8);
#pragma unroll
        for (int mi = 0; mi < 2; mi++)
#pragma unroll
            for (int ni = 0; ni < 4; ni++)
                acc[mi][ni] = __builtin_amdgcn_mfma_f32_16x16x32_bf16(
                    af[mi], bfr[ni], acc[mi][ni], 0, 0, 0);
    }

#pragma unroll
    for (int ni = 0; ni < 4; ni++) {
        int col = bn + ni * 16 + lm;
        float bv = bias[col];
#pragma unroll
        for (int mi = 0; mi < 2; mi++) {
#pragma unroll
            for (int r = 0; r < 4; r++) {
                int rowg = bm + w * 32 + mi * 16 + quad * 4 + r;
                out[(size_t)rowg * DMODEL + col] = acc[mi][ni][r] + bv;
            }
        }
    }
}

// ---------------- Flash attention v4: S^T formulation ----------------
// grid (SEQ/128, B*NH), 4 waves; wave w owns q-rows w*32..w*32+31 (2 n-tiles).
// S^T = K·Q^T (A=K from LDS, B=Q from global regs) -> C: col=lane&15=qrow, row=quad*4+r=key.
// Softmax rows are per-lane: in-reg reduce + shfl_xor(16/32) only.
// PV: O^T += V^T·P^T via 16x16x16 MFMA; P^T B-frag == S^T C-regs (no LDS transpose).
#define SP 72
__global__ __launch_bounds__(256, 2) void attn_kernel(
    const u16* __restrict__ q, const u16* __restrict__ k,
    const u16* __restrict__ vt, u16* __restrict__ out)
{
    __shared__ __align__(16) u16 Ks[64 * SP];   // [key][d]
    __shared__ __align__(16) u16 Vs[64 * SP];   // [d][key]
    const int tid = threadIdx.x, l = tid & 63, w = tid >> 6;
    const int lm = l & 15, quad = l >> 4;
    const int qt = blockIdx.x, bh = blockIdx.y;
    const int b = bh >> 4, h = bh & 15;

    // Q B-frags straight from global: B[n=qrow][k=d], lane n=lm holds d=ks*32+quad*8+j
    bf16x8 qf[2][2];
#pragma unroll
    for (int nt = 0; nt < 2; nt++) {
        int row = qt * 128 + w * 32 + nt * 16 + lm;
        const u16* qp = q + ((size_t)bh * SEQ + row) * DH;
#pragma unroll
        for (int ks = 0; ks < 2; ks++)
            qf[nt][ks] = *(const bf16x8*)(qp + ks * 32 + quad * 8);
    }

    floatx4 O[4][2];   // O^T accum: [d-tile][n-tile], D[m=d][n=qrow]
#pragma unroll
    for (int dt = 0; dt < 4; dt++)
#pragma unroll
        for (int nt = 0; nt < 2; nt++) O[dt][nt] = (floatx4){0.f, 0.f, 0.f, 0.f};
    float mrun[2] = {-1e30f, -1e30f}, lrun[2] = {0.f, 0.f};

    const int srow = tid >> 3, scol = (tid & 7) * 8;
    const u16* kbase = k + (size_t)bh * SEQ * DH;
    const u16* vbase = vt + (size_t)bh * DH * SEQ;
    uint4 kr0, kr1, vr0, vr1;
    kr0 = *(const uint4*)(kbase + (size_t)srow * DH + scol);
    kr1 = *(const uint4*)(kbase + (size_t)(srow + 32) * DH + scol);
    vr0 = *(const uint4*)(vbase + (size_t)srow * SEQ + scol);
    vr1 = *(const uint4*)(vbase + (size_t)(srow + 32) * SEQ + scol);

    for (int t = 0; t < SEQ / 64; t++) {
        __syncthreads();
        *(uint4*)(Ks + srow * SP + scol) = kr0;
        *(uint4*)(Ks + (srow + 32) * SP + scol) = kr1;
        *(uint4*)(Vs + srow * SP + scol) = vr0;
        *(uint4*)(Vs + (srow + 32) * SP + scol) = vr1;
        __syncthreads();
        if (t + 1 < SEQ / 64) {
            const u16* kg = kbase + (size_t)(t + 1) * 64 * DH;
            const u16* vg = vbase + (size_t)(t + 1) * 64;
            kr0 = *(const uint4*)(kg + (size_t)srow * DH + scol);
            kr1 = *(const uint4*)(kg + (size_t)(srow + 32) * DH + scol);
            vr0 = *(const uint4*)(vg + (size_t)srow * SEQ + scol);
            vr1 = *(const uint4*)(vg + (size_t)(srow + 32) * SEQ + scol);
        }

        // S^T = K·Q^T : Sc[mt][nt], lane holds keys mt*16+quad*4+r for qrow lm
        floatx4 Sc[4][2];
#pragma unroll
        for (int mt = 0; mt < 4; mt++) {
            bf16x8 ka0 = *(const bf16x8*)(Ks + (mt * 16 + lm) * SP + quad * 8);
            bf16x8 ka1 = *(const bf16x8*)(Ks + (mt * 16 + lm) * SP + 32 + quad * 8);
#pragma unroll
            for (int nt = 0; nt < 2; nt++) {
                floatx4 c = (floatx4){0.f, 0.f, 0.f, 0.f};
                c = __builtin_amdgcn_mfma_f32_16x16x32_bf16(ka0, qf[nt][0], c, 0, 0, 0);
                c = __builtin_amdgcn_mfma_f32_16x16x32_bf16(ka1, qf[nt][1], c, 0, 0, 0);
                Sc[mt][nt] = c;
            }
        }

        // online softmax: per-lane rows, 2 shuffles per reduction
        bf16x4 pb[4][2];
#pragma unroll
        for (int nt = 0; nt < 2; nt++) {
            float m0 = -1e30f;
#pragma unroll
            for (int mt = 0; mt < 4; mt++)
#pragma unroll
                for (int r = 0; r < 4; r++) m0 = fmaxf(m0, Sc[mt][nt][r]);
            m0 = fmaxf(m0, __shfl_xor(m0, 16));
            m0 = fmaxf(m0, __shfl_xor(m0, 32));
            float mn = fmaxf(mrun[nt], m0);
            float alpha = __expf(mrun[nt] - mn);
            mrun[nt] = mn;
            float s0 = 0.f;
#pragma unroll
            for (int mt = 0; mt < 4; mt++) {
#pragma unroll
                for (int r = 0; r < 4; r++) {
                    float e = __expf(Sc[mt][nt][r] - mn);
                    Sc[mt][nt][r] = e;
                    s0 += e;
                }
                pb[mt][nt] = (bf16x4){
                    (short)f2bf(Sc[mt][nt][0]), (short)f2bf(Sc[mt][nt][1]),
                    (short)f2bf(Sc[mt][nt][2]), (short)f2bf(Sc[mt][nt][3])};
            }
            s0 += __shfl_xor(s0, 16);
            s0 += __shfl_xor(s0, 32);
            lrun[nt] = lrun[nt] * alpha + s0;
#pragma unroll
            for (int dt = 0; dt < 4; dt++)
#pragma unroll
                for (int r = 0; r < 4; r++) O[dt][nt][r] *= alpha;
        }

        // O^T += V^T·P^T : A=V^T rows (m=d, k=quad*4+j), B=P^T from C-regs
#pragma unroll
        for (int mt = 0; mt < 4; mt++) {
#pragma unroll
            for (int dt = 0; dt < 4; dt++) {
                bf16x4 va = *(const bf16x4*)(Vs + (dt * 16 + lm) * SP + mt * 16 + quad * 4);
                O[dt][0] = mfma16(va, pb[mt][0], O[dt][0]);
                O[dt][1] = mfma16(va, pb[mt][1], O[dt][1]);
            }
        }
    }

    // epilogue: O^T C-layout -> out[B,S,D]: lane writes 4 consecutive d (8B)
#pragma unroll
    for (int nt = 0; nt < 2; nt++) {
        float inv = 1.0f / lrun[nt];
        int s = qt * 128 + w * 32 + nt * 16 + lm;
        u16* op = out + ((size_t)b * SEQ + s) * DMODEL + h * DH;
#pragma unroll
        for (int dt = 0; dt < 4; dt++) {
            u16x4 pk;
#pragma unroll
            for (int r = 0; r < 4; r++) pk[r] = f2bf(O[dt][nt][r] * inv);
            *(u16x4*)(op + dt * 16 + quad * 4) = pk;
        }
    }
}

extern "C" void kernel_launch(void* const* d_in, const int* in_sizes, int n_in,
                              void* d_out, int out_size, void* d_ws, size_t ws_size,
                              hipStream_t stream) {
    (void)in_sizes; (void)n_in; (void)out_size;
    const float* Q  = (const float*)d_in[0];
    const float* K  = (const float*)d_in[1];
    const float* V  = (const float*)d_in[2];
    const float* Wq = (const float*)d_in[3];
    const float* bq = (const float*)d_in[4];
    const float* Wk = (const float*)d_in[5];
    const float* bk = (const float*)d_in[6];
    const float* Wv = (const float*)d_in[7];
    const float* bv = (const float*)d_in[8];
    const float* Wo = (const float*)d_in[9];
    const float* bo = (const float*)d_in[10];

    const size_t NEL = (size_t)2 * NH * SEQ * DH;  // 4,194,304 elements
    u16* base = (u16*)d_ws;
    dim3 bb(256);

    if (ws_size >= 8 * NEL * 2) {
        u16* Qb   = base;
        u16* Kb   = Qb + NEL;
        u16* Vb   = Kb + NEL;
        u16* Wb   = Vb + NEL;
        u16* qws  = Wb + NEL;
        u16* kws  = qws + NEL;
        u16* vtws = kws + NEL;
        u16* aws  = vtws + NEL;
        cvt_all<<<dim3(2048, 7), bb, 0, stream>>>(Q, K, V, Wq, Wk, Wv, Wo, Qb, Kb, Vb, Wb);
        gemm_qkv_bb<<<dim3(8, 32, 3), bb, 0, stream>>>(
            Qb, Kb, Vb, Wb, bq, bk, bv, qws, kws, vtws);
        attn_kernel<<<dim3(SEQ / 128, 2 * NH), bb, 0, stream>>>(qws, kws, vtws, aws);
        gemm_o<true><<<dim3(16, 32), bb, 0, stream>>>(aws, Wb + 3145728, bo, (float*)d_out);
    } else if (ws_size >= 5 * NEL * 2) {
        u16* Wb = base;
        u16* qws = base + NEL; u16* kws = qws + NEL; u16* vtws = kws + NEL; u16* aws = vtws + NEL;
        cvt_w<<<dim3(512, 4), bb, 0, stream>>>(Wq, Wk, Wv, Wo, Wb);
        gemm_qkv<true><<<dim3(8, 32, 3), bb, 0, stream>>>(
            Q, K, V, Wb, Wb + 1048576, Wb + 2097152, bq, bk, bv, qws, kws, vtws);
        attn_kernel<<<dim3(SEQ / 128, 2 * NH), bb, 0, stream>>>(qws, kws, vtws, aws);
        gemm_o<true><<<dim3(16, 32), bb, 0, stream>>>(aws, Wb + 3145728, bo, (float*)d_out);
    } else {
        u16* qws = base; u16* kws = qws + NEL; u16* vtws = kws + NEL; u16* aws = vtws + NEL;
        gemm_qkv<false><<<dim3(8, 32, 3), bb, 0, stream>>>(
            Q, K, V, Wq, Wk, Wv, bq, bk, bv, qws, kws, vtws);
        attn_kernel<<<dim3(SEQ / 128, 2 * NH), bb, 0, stream>>>(qws, kws, vtws, aws);
        gemm_o<false><<<dim3(16, 32), bb, 0, stream>>>(aws, Wo, bo, (float*)d_out);
    }
}

// Round 9
// 244.950 us; speedup vs baseline: 1.8221x; 1.0322x over previous
//
#include <hip/hip_runtime.h>

#define SEQ 2048
#define DMODEL 1024
#define NH 16
#define DH 64

typedef __attribute__((ext_vector_type(8))) short bf16x8;
typedef __attribute__((ext_vector_type(4))) short bf16x4;
typedef __attribute__((ext_vector_type(4))) float floatx4;
typedef __attribute__((ext_vector_type(4))) unsigned short u16x4;
typedef unsigned short u16;
typedef unsigned int u32;

typedef const void __attribute__((address_space(1)))* as1cvp;
typedef void __attribute__((address_space(3)))* as3vp;

__device__ __forceinline__ void glds16(const void* g, void* l) {
    __builtin_amdgcn_global_load_lds((as1cvp)g, (as3vp)l, 16, 0, 0);
}

__device__ __forceinline__ u16 f2bf(float f) {
    union { u32 u; float f; } v; v.f = f;
    u32 r = v.u + 0x7fffu + ((v.u >> 16) & 1u);   // RNE
    return (u16)(r >> 16);
}

// packed f32->2xbf16, SOFTWARE RNE. (v_cvt_pk_bf16_f32 on gfx950 is NOT RNE —
// round-8 measured 33x absmax degradation, consistent with biased truncation.)
__device__ __forceinline__ u32 pk2(float a, float b) {
    return (u32)f2bf(a) | ((u32)f2bf(b) << 16);
}

// 16x16x16 bf16 MFMA: B-frag layout k=quad*4+j matches C-layout of S^T
__device__ __forceinline__ floatx4 mfma16(bf16x4 a, bf16x4 b, floatx4 c) {
#if __has_builtin(__builtin_amdgcn_mfma_f32_16x16x16bf16_1k)
    return __builtin_amdgcn_mfma_f32_16x16x16bf16_1k(a, b, c, 0, 0, 0);
#else
    asm volatile("v_mfma_f32_16x16x16_bf16 %0, %1, %2, %0" : "+v"(c) : "v"(a), "v"(b));
    return c;
#endif
}

__device__ __forceinline__ uint4 cvt8(const float* __restrict__ p) {
    float4 a = *(const float4*)p;
    float4 b = *(const float4*)(p + 4);
    uint4 q;
    q.x = pk2(a.x, a.y); q.y = pk2(a.z, a.w);
    q.z = pk2(b.x, b.y); q.w = pk2(b.z, b.w);
    return q;
}

// q pre-scale: 1/sqrt(Dh); __expf only (exp2f = slow OCML path, r5 regression)
#define QSCALE 0.125f

// ---------------- convert Q,K,V + 4 weights to bf16 once ----------------
__global__ __launch_bounds__(256) void cvt_all(
    const float* __restrict__ Q, const float* __restrict__ K, const float* __restrict__ V,
    const float* __restrict__ W0, const float* __restrict__ W1,
    const float* __restrict__ W2, const float* __restrict__ W3,
    u16* __restrict__ Qb, u16* __restrict__ Kb, u16* __restrict__ Vb,
    u16* __restrict__ Wb)
{
    const int y = blockIdx.y;
    const float* src; u16* dst;
    if (y == 0)      { src = Q;  dst = Qb; }
    else if (y == 1) { src = K;  dst = Kb; }
    else if (y == 2) { src = V;  dst = Vb; }
    else {
        if (blockIdx.x >= 512) return;
        src = (y == 3) ? W0 : (y == 4) ? W1 : (y == 5) ? W2 : W3;
        dst = Wb + (size_t)(y - 3) * 1048576;
    }
    size_t i = ((size_t)blockIdx.x * 256 + threadIdx.x) * 8;
    *(uint4*)(dst + i) = cvt8(src + i);
}

__global__ __launch_bounds__(256) void cvt_w(
    const float* __restrict__ W0, const float* __restrict__ W1,
    const float* __restrict__ W2, const float* __restrict__ W3,
    u16* __restrict__ out)
{
    const float* src = (blockIdx.y == 0) ? W0 : (blockIdx.y == 1) ? W1
                     : (blockIdx.y == 2) ? W2 : W3;
    size_t i = ((size_t)blockIdx.x * 256 + threadIdx.x) * 8;
    *(uint4*)(out + (size_t)blockIdx.y * 1048576 + i) = cvt8(src + i);
}

// shared epilogue store for QKV projections (z<2: scalar, z=2: vectorized 8B)
__device__ __forceinline__ void qkv_store(
    int z, u16* __restrict__ outp, int rowg, int col, floatx4 a4, float bv, float sc)
{
    union { u32 w[2]; u16 h[4]; u16x4 v4; } pk;
    pk.w[0] = pk2((a4[0] + bv) * sc, (a4[1] + bv) * sc);
    pk.w[1] = pk2((a4[2] + bv) * sc, (a4[3] + bv) * sc);
    int b = rowg >> 11, s = rowg & 2047, h = col >> 6, d = col & 63;
    if (z < 2) {
#pragma unroll
        for (int r = 0; r < 4; r++)
            outp[((size_t)(b * NH + h) * SEQ + s + r) * DH + d] = pk.h[r];
    } else {
        *(u16x4*)(outp + ((size_t)(b * NH + h) * DH + d) * SEQ + s) = pk.v4;
    }
}

// ---------------- QKV projection, both operands bf16, pure glds16 staging ----------------
__global__ __launch_bounds__(256) void gemm_qkv_bb(
    const u16* __restrict__ Qb, const u16* __restrict__ Kb, const u16* __restrict__ Vb,
    const u16* __restrict__ Wb,
    const float* __restrict__ b0, const float* __restrict__ b1, const float* __restrict__ b2,
    u16* __restrict__ qo, u16* __restrict__ ko, u16* __restrict__ vto)
{
    __shared__ __align__(16) u16 As[128 * 32];
    __shared__ __align__(16) u16 Bs[128 * 32];
    const int tid = threadIdx.x, l = tid & 63, w = tid >> 6;
    const int lm = l & 15, quad = l >> 4;
    const int wr = (w >> 1) * 64, wc = (w & 1) * 64;
    const int bm = blockIdx.y * 128, bn = blockIdx.x * 128;
    const int z = blockIdx.z;
    const u16* A      = (z == 0) ? Qb : (z == 1) ? Kb : Vb;
    const u16* W      = Wb + (size_t)z * 1048576;
    const float* bias = (z == 0) ? b0 : (z == 1) ? b1 : b2;

    const int srow = tid >> 2, scol = (tid & 3) * 8;

    floatx4 acc[4][4];
#pragma unroll
    for (int i = 0; i < 4; i++)
#pragma unroll
        for (int j = 0; j < 4; j++) acc[i][j] = (floatx4){0.f, 0.f, 0.f, 0.f};

    for (int kt = 0; kt < DMODEL; kt += 32) {
        __syncthreads();
        glds16(A + (size_t)(bm + srow) * DMODEL + kt + scol, As + w * 512);
        glds16(A + (size_t)(bm + 64 + srow) * DMODEL + kt + scol, As + 2048 + w * 512);
        glds16(W + (size_t)(bn + srow) * DMODEL + kt + scol, Bs + w * 512);
        glds16(W + (size_t)(bn + 64 + srow) * DMODEL + kt + scol, Bs + 2048 + w * 512);
        __syncthreads();

        bf16x8 af[4], bfr[4];
#pragma unroll
        for (int mi = 0; mi < 4; mi++)
            af[mi] = *(const bf16x8*)(As + (wr + mi * 16 + lm) * 32 + quad * 8);
#pragma unroll
        for (int ni = 0; ni < 4; ni++)
            bfr[ni] = *(const bf16x8*)(Bs + (wc + ni * 16 + lm) * 32 + quad * 8);
#pragma unroll
        for (int mi = 0; mi < 4; mi++)
#pragma unroll
            for (int ni = 0; ni < 4; ni++)
                acc[mi][ni] = __builtin_amdgcn_mfma_f32_16x16x32_bf16(
                    af[mi], bfr[ni], acc[mi][ni], 0, 0, 0);
    }

    const float sc = (z == 0) ? QSCALE : 1.0f;
    u16* outp = (z == 0) ? qo : (z == 1) ? ko : vto;
#pragma unroll
    for (int ni = 0; ni < 4; ni++) {
        int col = bn + wc + ni * 16 + lm;
        float bv = bias[col];
#pragma unroll
        for (int mi = 0; mi < 4; mi++)
            qkv_store(z, outp, bm + wr + mi * 16 + quad * 4, col, acc[mi][ni], bv, sc);
    }
}

// ---------------- legacy QKV (A f32 converted in staging) ----------------
template<bool WBF>
__global__ __launch_bounds__(256) void gemm_qkv(
    const float* __restrict__ Qf, const float* __restrict__ Kf, const float* __restrict__ Vf,
    const void* __restrict__ W0, const void* __restrict__ W1, const void* __restrict__ W2,
    const float* __restrict__ b0, const float* __restrict__ b1, const float* __restrict__ b2,
    u16* __restrict__ qo, u16* __restrict__ ko, u16* __restrict__ vto)
{
    __shared__ __align__(16) u16 As[128 * 32];
    __shared__ __align__(16) u16 Bs[128 * 32];
    const int tid = threadIdx.x, l = tid & 63, w = tid >> 6;
    const int lm = l & 15, quad = l >> 4;
    const int wr = (w >> 1) * 64, wc = (w & 1) * 64;
    const int bm = blockIdx.y * 128, bn = blockIdx.x * 128;
    const int z = blockIdx.z;
    const float* A    = (z == 0) ? Qf : (z == 1) ? Kf : Vf;
    const void* Wp    = (z == 0) ? W0 : (z == 1) ? W1 : W2;
    const float* bias = (z == 0) ? b0 : (z == 1) ? b1 : b2;

    floatx4 acc[4][4];
#pragma unroll
    for (int i = 0; i < 4; i++)
#pragma unroll
        for (int j = 0; j < 4; j++) acc[i][j] = (floatx4){0.f, 0.f, 0.f, 0.f};

    for (int kt = 0; kt < DMODEL; kt += 32) {
        __syncthreads();
#pragma unroll
        for (int j = 0; j < 2; j++) {
            int ch = j * 256 + tid, row = ch >> 2, c = ch & 3;
            *(uint4*)(As + ch * 8) = cvt8(A + (size_t)(bm + row) * DMODEL + kt + c * 8);
        }
        if (WBF) {
            const u16* Wb = (const u16*)Wp;
            glds16(Wb + (size_t)(bn + (tid >> 2)) * DMODEL + kt + (tid & 3) * 8, Bs + w * 512);
            glds16(Wb + (size_t)(bn + 64 + (tid >> 2)) * DMODEL + kt + (tid & 3) * 8, Bs + 2048 + w * 512);
        } else {
            const float* Wf = (const float*)Wp;
#pragma unroll
            for (int j = 0; j < 2; j++) {
                int ch = j * 256 + tid, row = ch >> 2, c = ch & 3;
                *(uint4*)(Bs + ch * 8) = cvt8(Wf + (size_t)(bn + row) * DMODEL + kt + c * 8);
            }
        }
        __syncthreads();

        bf16x8 af[4], bfr[4];
#pragma unroll
        for (int mi = 0; mi < 4; mi++)
            af[mi] = *(const bf16x8*)(As + (wr + mi * 16 + lm) * 32 + quad * 8);
#pragma unroll
        for (int ni = 0; ni < 4; ni++)
            bfr[ni] = *(const bf16x8*)(Bs + (wc + ni * 16 + lm) * 32 + quad * 8);
#pragma unroll
        for (int mi = 0; mi < 4; mi++)
#pragma unroll
            for (int ni = 0; ni < 4; ni++)
                acc[mi][ni] = __builtin_amdgcn_mfma_f32_16x16x32_bf16(
                    af[mi], bfr[ni], acc[mi][ni], 0, 0, 0);
    }

    const float sc = (z == 0) ? QSCALE : 1.0f;
    u16* outp = (z == 0) ? qo : (z == 1) ? ko : vto;
#pragma unroll
    for (int ni = 0; ni < 4; ni++) {
        int col = bn + wc + ni * 16 + lm;
        float bv = bias[col];
#pragma unroll
        for (int mi = 0; mi < 4; mi++)
            qkv_store(z, outp, bm + wr + mi * 16 + quad * 4, col, acc[mi][ni], bv, sc);
    }
}

// ---------------- O-projection: A bf16, W bf16/f32, out f32. 128x64 tiles ----------------
template<bool WBF>
__global__ __launch_bounds__(256) void gemm_o(
    const u16* __restrict__ A, const void* __restrict__ Wp,
    const float* __restrict__ bias, float* __restrict__ out)
{
    __shared__ __align__(16) u16 As[128 * 32];
    __shared__ __align__(16) u16 Bs[64 * 32];
    const int tid = threadIdx.x, l = tid & 63, w = tid >> 6;
    const int lm = l & 15, quad = l >> 4;
    const int bm = blockIdx.y * 128, bn = blockIdx.x * 64;

    floatx4 acc[2][4];
#pragma unroll
    for (int i = 0; i < 2; i++)
#pragma unroll
        for (int j = 0; j < 4; j++) acc[i][j] = (floatx4){0.f, 0.f, 0.f, 0.f};

    for (int kt = 0; kt < DMODEL; kt += 32) {
        __syncthreads();
        glds16(A + (size_t)(bm + (tid >> 2)) * DMODEL + kt + (tid & 3) * 8, As + w * 512);
        glds16(A + (size_t)(bm + 64 + (tid >> 2)) * DMODEL + kt + (tid & 3) * 8, As + 2048 + w * 512);
        if (WBF) {
            glds16((const u16*)Wp + (size_t)(bn + (tid >> 2)) * DMODEL + kt + (tid & 3) * 8, Bs + w * 512);
        } else {
            *(uint4*)(Bs + tid * 8) =
                cvt8((const float*)Wp + (size_t)(bn + (tid >> 2)) * DMODEL + kt + (tid & 3) * 8);
        }
        __syncthreads();

        bf16x8 af[2], bfr[4];
#pragma unroll
        for (int mi = 0; mi < 2; mi++)
            af[mi] = *(const bf16x8*)(As + (w * 32 + mi * 16 + lm) * 32 + quad * 8);
#pragma unroll
        for (int ni = 0; ni < 4; ni++)
            bfr[ni] = *(const bf16x8*)(Bs + (ni * 16 + lm) * 32 + quad * 8);
#pragma unroll
        for (int mi = 0; mi < 2; mi++)
#pragma unroll
            for (int ni = 0; ni < 4; ni++)
                acc[mi][ni] = __builtin_amdgcn_mfma_f32_16x16x32_bf16(
                    af[mi], bfr[ni], acc[mi][ni], 0, 0, 0);
    }

#pragma unroll
    for (int ni = 0; ni < 4; ni++) {
        int col = bn + ni * 16 + lm;
        float bv = bias[col];
#pragma unroll
        for (int mi = 0; mi < 2; mi++) {
#pragma unroll
            for (int r = 0; r < 4; r++) {
                int rowg = bm + w * 32 + mi * 16 + quad * 4 + r;
                out[(size_t)rowg * DMODEL + col] = acc[mi][ni][r] + bv;
            }
        }
    }
}

// ---------------- Flash attention v5b: S^T formulation, permuted Vs, software-RNE cvt ----------------
// grid (SEQ/128, B*NH), 4 waves; wave w owns q-rows w*32..w*32+31 (2 n-tiles).
// S^T = K·Q^T -> C: col=lane&15=qrow, row=quad*4+r=key; softmax rows per-lane.
// Vs stores keys PERMUTED: key m=mt*16+q*4+j at pos q*16+mt*4+j, so a lane's PV
// A-frags for all 4 mt are 16 contiguous u16 -> 2 x ds_read_b128 per dt.
#define SP 72
__global__ __launch_bounds__(256, 2) void attn_kernel(
    const u16* __restrict__ q, const u16* __restrict__ k,
    const u16* __restrict__ vt, u16* __restrict__ out)
{
    __shared__ __align__(16) u16 Ks[64 * SP];   // [key][d]
    __shared__ __align__(16) u16 Vs[64 * SP];   // [d][key-permuted]
    const int tid = threadIdx.x, l = tid & 63, w = tid >> 6;
    const int lm = l & 15, quad = l >> 4;
    const int qt = blockIdx.x, bh = blockIdx.y;
    const int b = bh >> 4, h = bh & 15;

    bf16x8 qf[2][2];
#pragma unroll
    for (int nt = 0; nt < 2; nt++) {
        int row = qt * 128 + w * 32 + nt * 16 + lm;
        const u16* qp = q + ((size_t)bh * SEQ + row) * DH;
#pragma unroll
        for (int ks = 0; ks < 2; ks++)
            qf[nt][ks] = *(const bf16x8*)(qp + ks * 32 + quad * 8);
    }

    floatx4 O[4][2];
#pragma unroll
    for (int dt = 0; dt < 4; dt++)
#pragma unroll
        for (int nt = 0; nt < 2; nt++) O[dt][nt] = (floatx4){0.f, 0.f, 0.f, 0.f};
    float mrun[2] = {-1e30f, -1e30f}, lrun[2] = {0.f, 0.f};

    const int srow = tid >> 3, scol = (tid & 7) * 8;
    // permuted V position base: chunk scol..scol+3 -> pb0, scol+4..scol+7 -> pb0+16
    const int pb0 = ((scol >> 2) & 3) * 16 + (scol >> 4) * 4;
    const u16* kbase = k + (size_t)bh * SEQ * DH;
    const u16* vbase = vt + (size_t)bh * DH * SEQ;
    uint4 kr0, kr1, vr0, vr1;
    kr0 = *(const uint4*)(kbase + (size_t)srow * DH + scol);
    kr1 = *(const uint4*)(kbase + (size_t)(srow + 32) * DH + scol);
    vr0 = *(const uint4*)(vbase + (size_t)srow * SEQ + scol);
    vr1 = *(const uint4*)(vbase + (size_t)(srow + 32) * SEQ + scol);

    for (int t = 0; t < SEQ / 64; t++) {
        __syncthreads();
        *(uint4*)(Ks + srow * SP + scol) = kr0;
        *(uint4*)(Ks + (srow + 32) * SP + scol) = kr1;
        *(uint2*)(Vs + srow * SP + pb0)             = make_uint2(vr0.x, vr0.y);
        *(uint2*)(Vs + srow * SP + pb0 + 16)        = make_uint2(vr0.z, vr0.w);
        *(uint2*)(Vs + (srow + 32) * SP + pb0)      = make_uint2(vr1.x, vr1.y);
        *(uint2*)(Vs + (srow + 32) * SP + pb0 + 16) = make_uint2(vr1.z, vr1.w);
        __syncthreads();
        if (t + 1 < SEQ / 64) {
            const u16* kg = kbase + (size_t)(t + 1) * 64 * DH;
            const u16* vg = vbase + (size_t)(t + 1) * 64;
            kr0 = *(const uint4*)(kg + (size_t)srow * DH + scol);
            kr1 = *(const uint4*)(kg + (size_t)(srow + 32) * DH + scol);
            vr0 = *(const uint4*)(vg + (size_t)srow * SEQ + scol);
            vr1 = *(const uint4*)(vg + (size_t)(srow + 32) * SEQ + scol);
        }

        // S^T = K·Q^T
        floatx4 Sc[4][2];
#pragma unroll
        for (int mt = 0; mt < 4; mt++) {
            bf16x8 ka0 = *(const bf16x8*)(Ks + (mt * 16 + lm) * SP + quad * 8);
            bf16x8 ka1 = *(const bf16x8*)(Ks + (mt * 16 + lm) * SP + 32 + quad * 8);
#pragma unroll
            for (int nt = 0; nt < 2; nt++) {
                floatx4 c = (floatx4){0.f, 0.f, 0.f, 0.f};
                c = __builtin_amdgcn_mfma_f32_16x16x32_bf16(ka0, qf[nt][0], c, 0, 0, 0);
                c = __builtin_amdgcn_mfma_f32_16x16x32_bf16(ka1, qf[nt][1], c, 0, 0, 0);
                Sc[mt][nt] = c;
            }
        }

        // online softmax: per-lane rows, 2 shuffles per reduction
        bf16x4 pb[4][2];
#pragma unroll
        for (int nt = 0; nt < 2; nt++) {
            float m0 = -1e30f;
#pragma unroll
            for (int mt = 0; mt < 4; mt++)
#pragma unroll
                for (int r = 0; r < 4; r++) m0 = fmaxf(m0, Sc[mt][nt][r]);
            m0 = fmaxf(m0, __shfl_xor(m0, 16));
            m0 = fmaxf(m0, __shfl_xor(m0, 32));
            float mn = fmaxf(mrun[nt], m0);
            float alpha = __expf(mrun[nt] - mn);
            mrun[nt] = mn;
            float s0 = 0.f;
#pragma unroll
            for (int mt = 0; mt < 4; mt++) {
#pragma unroll
                for (int r = 0; r < 4; r++) {
                    float e = __expf(Sc[mt][nt][r] - mn);
                    Sc[mt][nt][r] = e;
                    s0 += e;
                }
                union { u32 w2[2]; bf16x4 v; } pku;
                pku.w2[0] = pk2(Sc[mt][nt][0], Sc[mt][nt][1]);
                pku.w2[1] = pk2(Sc[mt][nt][2], Sc[mt][nt][3]);
                pb[mt][nt] = pku.v;
            }
            s0 += __shfl_xor(s0, 16);
            s0 += __shfl_xor(s0, 32);
            lrun[nt] = lrun[nt] * alpha + s0;
#pragma unroll
            for (int dt = 0; dt < 4; dt++)
#pragma unroll
                for (int r = 0; r < 4; r++) O[dt][nt][r] *= alpha;
        }

        // O^T += V^T·P^T : permuted Vs -> 2 b128 reads per dt cover all 4 mt frags
#pragma unroll
        for (int dt = 0; dt < 4; dt++) {
            const u16* vp = Vs + (dt * 16 + lm) * SP + quad * 16;
            bf16x8 v8a = *(const bf16x8*)vp;        // mt 0 (elems 0-3), mt 1 (4-7)
            bf16x8 v8b = *(const bf16x8*)(vp + 8);  // mt 2, mt 3
            bf16x4 va0 = __builtin_shufflevector(v8a, v8a, 0, 1, 2, 3);
            bf16x4 va1 = __builtin_shufflevector(v8a, v8a, 4, 5, 6, 7);
            bf16x4 va2 = __builtin_shufflevector(v8b, v8b, 0, 1, 2, 3);
            bf16x4 va3 = __builtin_shufflevector(v8b, v8b, 4, 5, 6, 7);
            O[dt][0] = mfma16(va0, pb[0][0], O[dt][0]);
            O[dt][1] = mfma16(va0, pb[0][1], O[dt][1]);
            O[dt][0] = mfma16(va1, pb[1][0], O[dt][0]);
            O[dt][1] = mfma16(va1, pb[1][1], O[dt][1]);
            O[dt][0] = mfma16(va2, pb[2][0], O[dt][0]);
            O[dt][1] = mfma16(va2, pb[2][1], O[dt][1]);
            O[dt][0] = mfma16(va3, pb[3][0], O[dt][0]);
            O[dt][1] = mfma16(va3, pb[3][1], O[dt][1]);
        }
    }

    // epilogue: O^T C-layout -> out[B,S,D]: lane writes 4 consecutive d (8B)
#pragma unroll
    for (int nt = 0; nt < 2; nt++) {
        float inv = 1.0f / lrun[nt];
        int s = qt * 128 + w * 32 + nt * 16 + lm;
        u16* op = out + ((size_t)b * SEQ + s) * DMODEL + h * DH;
#pragma unroll
        for (int dt = 0; dt < 4; dt++) {
            union { u32 w2[2]; u16x4 v; } pku;
            pku.w2[0] = pk2(O[dt][nt][0] * inv, O[dt][nt][1] * inv);
            pku.w2[1] = pk2(O[dt][nt][2] * inv, O[dt][nt][3] * inv);
            *(u16x4*)(op + dt * 16 + quad * 4) = pku.v;
        }
    }
}

extern "C" void kernel_launch(void* const* d_in, const int* in_sizes, int n_in,
                              void* d_out, int out_size, void* d_ws, size_t ws_size,
                              hipStream_t stream) {
    (void)in_sizes; (void)n_in; (void)out_size;
    const float* Q  = (const float*)d_in[0];
    const float* K  = (const float*)d_in[1];
    const float* V  = (const float*)d_in[2];
    const float* Wq = (const float*)d_in[3];
    const float* bq = (const float*)d_in[4];
    const float* Wk = (const float*)d_in[5];
    const float* bk = (const float*)d_in[6];
    const float* Wv = (const float*)d_in[7];
    const float* bv = (const float*)d_in[8];
    const float* Wo = (const float*)d_in[9];
    const float* bo = (const float*)d_in[10];

    const size_t NEL = (size_t)2 * NH * SEQ * DH;  // 4,194,304 elements
    u16* base = (u16*)d_ws;
    dim3 bb(256);

    if (ws_size >= 8 * NEL * 2) {
        u16* Qb   = base;
        u16* Kb   = Qb + NEL;
        u16* Vb   = Kb + NEL;
        u16* Wb   = Vb + NEL;
        u16* qws  = Wb + NEL;
        u16* kws  = qws + NEL;
        u16* vtws = kws + NEL;
        u16* aws  = vtws + NEL;
        cvt_all<<<dim3(2048, 7), bb, 0, stream>>>(Q, K, V, Wq, Wk, Wv, Wo, Qb, Kb, Vb, Wb);
        gemm_qkv_bb<<<dim3(8, 32, 3), bb, 0, stream>>>(
            Qb, Kb, Vb, Wb, bq, bk, bv, qws, kws, vtws);
        attn_kernel<<<dim3(SEQ / 128, 2 * NH), bb, 0, stream>>>(qws, kws, vtws, aws);
        gemm_o<true><<<dim3(16, 32), bb, 0, stream>>>(aws, Wb + 3145728, bo, (float*)d_out);
    } else if (ws_size >= 5 * NEL * 2) {
        u16* Wb = base;
        u16* qws = base + NEL; u16* kws = qws + NEL; u16* vtws = kws + NEL; u16* aws = vtws + NEL;
        cvt_w<<<dim3(512, 4), bb, 0, stream>>>(Wq, Wk, Wv, Wo, Wb);
        gemm_qkv<true><<<dim3(8, 32, 3), bb, 0, stream>>>(
            Q, K, V, Wb, Wb + 1048576, Wb + 2097152, bq, bk, bv, qws, kws, vtws);
        attn_kernel<<<dim3(SEQ / 128, 2 * NH), bb, 0, stream>>>(qws, kws, vtws, aws);
        gemm_o<true><<<dim3(16, 32), bb, 0, stream>>>(aws, Wb + 3145728, bo, (float*)d_out);
    } else {
        u16* qws = base; u16* kws = qws + NEL; u16* vtws = kws + NEL; u16* aws = vtws + NEL;
        gemm_qkv<false><<<dim3(8, 32, 3), bb, 0, stream>>>(
            Q, K, V, Wq, Wk, Wv, bq, bk, bv, qws, kws, vtws);
        attn_kernel<<<dim3(SEQ / 128, 2 * NH), bb, 0, stream>>>(qws, kws, vtws, aws);
        gemm_o<false><<<dim3(16, 32), bb, 0, stream>>>(aws, Wo, bo, (float*)d_out);
    }
}